// Round 7
// baseline (1105.000 us; speedup 1.0000x reference)
//
#include <hip/hip_runtime.h>
#include <hip/hip_bf16.h>

// Problem constants
#define Bc   2
#define Cc   192
#define NHc  6
#define HDc  32
#define Dd   16
#define Hh   32
#define Ww   32
#define Nn   16384          // Dd*Hh*Ww
#define SCALEc 0.17677669529663687f   // 32^-0.5

// d_out layout (floats):
//   out        [B,192,N]      @ 0          (6291456)
//   offs       [B,6,N,3]      @ 6291456    (589824)
//   offset_mag [B,6]      @ 6881280    (12)
//   branch_en  [B,2]      @ 6881292    (4)
//   guide      [B,8]      @ 6881296    (16)
#define OUT_OFFS   6291456
#define OUT_MAG    6881280
#define OUT_EN     6881292
#define OUT_GUIDE  6881296

#define BIG 6291456   // B*C*N floats
// ws layout (floats): q_p @0, k_t @BIG, v_t @2BIG, ol(lepe->o+lepe) @3BIG,
//                     t_dw @4BIG, t3 @5BIG (589824), pm (96), pe (1536)

// ---------------------------------------------------------------------------
// K1: fused QKV projection GEMM.  rows 0..575 = [qw;kw;vw] @ x  (+bias)
// q -> planar [b,c,n];  k,v -> transposed [bh,n,32]
// ---------------------------------------------------------------------------
__global__ __launch_bounds__(256) void gemm_qkv(
    const float* __restrict__ x,
    const float* __restrict__ qw, const float* __restrict__ qb,
    const float* __restrict__ kw, const float* __restrict__ kb,
    const float* __restrict__ vw, const float* __restrict__ vb,
    float* __restrict__ q_p, float* __restrict__ k_t, float* __restrict__ v_t)
{
    __shared__ float Wt[32][68];   // [kk][row]
    __shared__ float Xt[32][68];   // [kk][col]
    const int tid = threadIdx.x;
    const int RO = blockIdx.y * 64;           // 0..512
    const int CO = blockIdx.x * 64;           // 0..32704
    const int b  = CO >> 14;
    const int n0 = CO & 16383;
    const int proj = RO / 192;
    const int wr0  = RO % 192;
    const float* wsel = (proj == 0) ? qw : (proj == 1) ? kw : vw;
    const float* bsel = (proj == 0) ? qb : (proj == 1) ? kb : vb;
    const float* xb = x + (size_t)b * Cc * Nn;

    float acc[4][4] = {};
    const int ty = tid >> 4, tx = tid & 15;

    for (int k0 = 0; k0 < 192; k0 += 32) {
#pragma unroll
        for (int i = 0; i < 2; ++i) {         // W tile: 64 rows x 32 k
            int li = tid + i * 256;
            int row = li >> 3;
            int kq = (li & 7) * 4;
            float4 wv = *(const float4*)(wsel + (size_t)(wr0 + row) * 192 + k0 + kq);
            Wt[kq + 0][row] = wv.x; Wt[kq + 1][row] = wv.y;
            Wt[kq + 2][row] = wv.z; Wt[kq + 3][row] = wv.w;
        }
#pragma unroll
        for (int i = 0; i < 2; ++i) {         // X tile: 32 k x 64 cols
            int li = tid + i * 256;
            int kk = li >> 4;
            int c4 = (li & 15) * 4;
            float4 xv = *(const float4*)(xb + (size_t)(k0 + kk) * Nn + n0 + c4);
            *(float4*)&Xt[kk][c4] = xv;
        }
        __syncthreads();
#pragma unroll
        for (int kk = 0; kk < 32; ++kk) {
            float4 av = *(const float4*)&Wt[kk][ty * 4];
            float4 bv = *(const float4*)&Xt[kk][tx * 4];
            acc[0][0] += av.x * bv.x; acc[0][1] += av.x * bv.y; acc[0][2] += av.x * bv.z; acc[0][3] += av.x * bv.w;
            acc[1][0] += av.y * bv.x; acc[1][1] += av.y * bv.y; acc[1][2] += av.y * bv.z; acc[1][3] += av.y * bv.w;
            acc[2][0] += av.z * bv.x; acc[2][1] += av.z * bv.y; acc[2][2] += av.z * bv.z; acc[2][3] += av.z * bv.w;
            acc[3][0] += av.w * bv.x; acc[3][1] += av.w * bv.y; acc[3][2] += av.w * bv.z; acc[3][3] += av.w * bv.w;
        }
        __syncthreads();
    }

#pragma unroll
    for (int i = 0; i < 4; ++i) {
        int wr = wr0 + ty * 4 + i;
        float bias = bsel[wr];
        int hh = wr >> 5, dd = wr & 31;
#pragma unroll
        for (int j = 0; j < 4; ++j) {
            int n = n0 + tx * 4 + j;
            float v = acc[i][j] + bias;
            if (proj == 0) {
                q_p[((size_t)(b * Cc + wr)) * Nn + n] = v;
            } else {
                float* tdst = (proj == 1) ? k_t : v_t;
                tdst[((size_t)((b * NHc + hh) * Nn + n)) * HDc + dd] = v;
            }
        }
    }
}

// ---------------------------------------------------------------------------
// K2: two depthwise 3x3x3 convs (zero pad) over q: lepe (rpew) and t (odw)
// ---------------------------------------------------------------------------
__global__ __launch_bounds__(256) void dwconv2(
    const float* __restrict__ q_p,
    const float* __restrict__ rpew, const float* __restrict__ rpeb,
    const float* __restrict__ odw,  const float* __restrict__ odb,
    float* __restrict__ lepe, float* __restrict__ t_dw)
{
    int idx = blockIdx.x * 256 + threadIdx.x;     // < 6291456
    int n = idx & 16383;
    int bc = idx >> 14;
    int c = bc % Cc;
    int x = n & 31, y = (n >> 5) & 31, z = n >> 10;
    const float* src = q_p + (size_t)bc * Nn;
    float a1 = 0.f, a2 = 0.f;
#pragma unroll
    for (int kz = 0; kz < 3; ++kz) {
        int zz = z + kz - 1; bool zok = ((unsigned)zz < (unsigned)Dd);
#pragma unroll
        for (int ky = 0; ky < 3; ++ky) {
            int yy = y + ky - 1; bool yok = ((unsigned)yy < (unsigned)Hh);
#pragma unroll
            for (int kx = 0; kx < 3; ++kx) {
                int xx = x + kx - 1; bool xok = ((unsigned)xx < (unsigned)Ww);
                if (zok && yok && xok) {
                    float v = src[(zz * 32 + yy) * 32 + xx];
                    int wi = c * 27 + kz * 9 + ky * 3 + kx;
                    a1 += rpew[wi] * v;
                    a2 += odw[wi] * v;
                }
            }
        }
    }
    lepe[idx] = a1 + rpeb[c];
    t_dw[idx] = a2 + odb[c];
}

// ---------------------------------------------------------------------------
// K3: channel-LN + exact GeLU + 18-row offset projection + tanh
// ---------------------------------------------------------------------------
__global__ __launch_bounds__(256) void ln_offs(
    const float* __restrict__ t_dw,
    const float* __restrict__ lnw, const float* __restrict__ lnb,
    const float* __restrict__ opw, const float* __restrict__ opb,
    float* __restrict__ t3, float* __restrict__ offs_out)
{
    __shared__ float s_stat[2][4][64];
    __shared__ float s_acc[4][18][64];
    const int tid = threadIdx.x;
    const int p = tid >> 6;          // channel part 0..3
    const int l = tid & 63;          // position within block
    const int gb = blockIdx.x;       // 0..511
    const int b = gb >> 8;
    const int n = (gb & 255) * 64 + l;
    const float* src = t_dw + (size_t)b * Cc * Nn + n;

    float s = 0.f, s2 = 0.f;
    for (int c = p * 48; c < p * 48 + 48; ++c) {
        float v = src[(size_t)c * Nn];
        s += v; s2 += v * v;
    }
    s_stat[0][p][l] = s; s_stat[1][p][l] = s2;
    __syncthreads();
    float st  = s_stat[0][0][l] + s_stat[0][1][l] + s_stat[0][2][l] + s_stat[0][3][l];
    float st2 = s_stat[1][0][l] + s_stat[1][1][l] + s_stat[1][2][l] + s_stat[1][3][l];
    float mean = st * (1.f / 192.f);
    float var  = st2 * (1.f / 192.f) - mean * mean;
    float rstd = rsqrtf(var + 1e-5f);

    float acc[18] = {};
    for (int c = p * 48; c < p * 48 + 48; ++c) {
        float v = src[(size_t)c * Nn];
        float xn = (v - mean) * rstd;
        float yv = xn * lnw[c] + lnb[c];
        float g = 0.5f * yv * (1.f + erff(yv * 0.70710678118654752f));
#pragma unroll
        for (int r = 0; r < 18; ++r) acc[r] += opw[r * 192 + c] * g;
    }
#pragma unroll
    for (int r = 0; r < 18; ++r) s_acc[p][r][l] = acc[r];
    __syncthreads();

    if (p < 3) {
#pragma unroll
        for (int hp = 0; hp < 2; ++hp) {
            int hh = p * 2 + hp;
            size_t base = ((size_t)((b * NHc + hh) * Nn) + n) * 3;
#pragma unroll
            for (int i = 0; i < 3; ++i) {
                int r = hh * 3 + i;
                float v = s_acc[0][r][l] + s_acc[1][r][l] + s_acc[2][r][l] + s_acc[3][r][l] + opb[r];
                float t = tanhf(v);
                float sc = (i == 2) ? (2.f / 15.f) : (2.f / 31.f);
                t3[base + i] = t;
                offs_out[base + i] = t * sc;
            }
        }
    }
}

// ---------------------------------------------------------------------------
// K4: deformable attention v3 — 2 threads per query, XCD swizzle, and
// 4x4x4 corner-dedup for the dil=1 heads (216 -> 64 gathered rows/pass).
// ---------------------------------------------------------------------------
__device__ __forceinline__ float dot16(const float4* q4, const float* r) {
    const float4* r4 = (const float4*)r;
    float s = 0.f;
#pragma unroll
    for (int i = 0; i < 4; ++i) {
        float4 a = q4[i], b = r4[i];
        s += a.x * b.x + a.y * b.y + a.z * b.z + a.w * b.w;
    }
    return s;
}

__device__ __forceinline__ void axpy16(float4* acc, float w, const float* r) {
    const float4* r4 = (const float4*)r;
#pragma unroll
    for (int i = 0; i < 4; ++i) {
        float4 b = r4[i];
        acc[i].x += w * b.x; acc[i].y += w * b.y;
        acc[i].z += w * b.z; acc[i].w += w * b.w;
    }
}

__global__ __launch_bounds__(256, 4) void attn_kernel(
    const float* __restrict__ q_p, const float* __restrict__ k_t,
    const float* __restrict__ v_t, const float* __restrict__ t3,
    const float* __restrict__ bias0, const float* __restrict__ bias1,
    float* __restrict__ ol, float* __restrict__ pe)
{
    __shared__ float s_sc[27 * 128];   // raw scores, one slot per query
    __shared__ float s_red[4];
    const int tid = threadIdx.x;
    // XCD-aware bijective swizzle: 1536 = 8 * 192
    const int wid = (blockIdx.x & 7) * 192 + (blockIdx.x >> 3);
    const int bh = wid >> 7;           // 128 blocks per bh
    const int nt = wid & 127;
    const int qi = tid >> 1;           // query within block 0..127
    const int hf = tid & 1;            // head-dim half
    const int n = nt * 128 + qi;
    const int b = bh / NHc, h = bh % NHc;
    const int dil = (h < 3) ? 1 : 2;
    const float* brow = (h < 3) ? (bias0 + h * 27) : (bias1 + (h - 3) * 27);
    const int x = n & 31, y = (n >> 5) & 31, z = n >> 10;

    const float* t3p = t3 + ((size_t)bh * Nn + n) * 3;
    const float pxb = (float)x + t3p[0];
    const float pyb = (float)y + t3p[1];
    const float pzb = (float)z + t3p[2];

    // per-axis per-sample clamp/floor precompute (all three axes)
    int xi0[3], xi1[3]; float xf[3], xg[3];
    int yi0[3], yi1[3]; float yf[3], yg[3];
    int zi0[3], zi1[3]; float zf[3], zg[3];
#pragma unroll
    for (int jj = 0; jj < 3; ++jj) {
        float p = fminf(fmaxf(pxb + (float)((jj - 1) * dil), 0.f), 31.f);
        float f0 = floorf(p); int i0 = (int)f0;
        xi0[jj] = i0 * HDc; xi1[jj] = min(i0 + 1, 31) * HDc;
        xf[jj] = p - f0; xg[jj] = 1.f - xf[jj];
        p = fminf(fmaxf(pyb + (float)((jj - 1) * dil), 0.f), 31.f);
        f0 = floorf(p); i0 = (int)f0;
        yi0[jj] = i0 * (Ww * HDc); yi1[jj] = min(i0 + 1, 31) * (Ww * HDc);
        yf[jj] = p - f0; yg[jj] = 1.f - yf[jj];
        p = fminf(fmaxf(pzb + (float)((jj - 1) * dil), 0.f), 15.f);
        f0 = floorf(p); i0 = (int)f0;
        zi0[jj] = i0 * (Hh * Ww * HDc); zi1[jj] = min(i0 + 1, 15) * (Hh * Ww * HDc);
        zf[jj] = p - f0; zg[jj] = 1.f - zf[jj];
    }

    // q half (16 dims) from planar layout: coalesced strided loads
    float4 qr[4];
    {
        const float* qsrc = q_p + ((size_t)(b * Cc + h * HDc + hf * 16)) * Nn + n;
#pragma unroll
        for (int i = 0; i < 4; ++i) {
            qr[i].x = qsrc[(size_t)(4 * i + 0) * Nn];
            qr[i].y = qsrc[(size_t)(4 * i + 1) * Nn];
            qr[i].z = qsrc[(size_t)(4 * i + 2) * Nn];
            qr[i].w = qsrc[(size_t)(4 * i + 3) * Nn];
        }
    }
    const float* kb = k_t + (size_t)bh * Nn * HDc + hf * 16;
    const float* vb = v_t + (size_t)bh * Nn * HDc + hf * 16;

    if (h < 3) {
        // ---------------- dil=1: 4x4x4 corner-dedup path ----------------
        // corner index lists; exact under clamping (disagreements have w=0)
        const int cxo[4] = { xi0[0], xi0[1], xi0[2], xi1[2] };
        const int cyo[4] = { yi0[0], yi0[1], yi0[2], yi1[2] };
        const int czo[4] = { zi0[0], zi0[1], zi0[2], zi1[2] };

        // pass 1: 64 unique dots, rolling 2-plane buffer, emit scores per jz
        float pl[2][16];
#pragma unroll
        for (int tz = 0; tz < 4; ++tz) {
            float* P = pl[tz & 1];
#pragma unroll
            for (int ty = 0; ty < 4; ++ty)
#pragma unroll
                for (int tx = 0; tx < 4; ++tx)
                    P[ty * 4 + tx] = dot16(qr, kb + czo[tz] + cyo[ty] + cxo[tx]);
            if (tz >= 1) {
                const int jz = tz - 1;
                const float* Pg = pl[jz & 1];        // plane tz == jz
                const float* Pf = pl[(jz + 1) & 1];  // plane tz == jz+1
#pragma unroll
                for (int jy = 0; jy < 3; ++jy)
#pragma unroll
                    for (int jx = 0; jx < 3; ++jx) {
                        float cg = yg[jy] * (xg[jx] * Pg[jy * 4 + jx] + xf[jx] * Pg[jy * 4 + jx + 1])
                                 + yf[jy] * (xg[jx] * Pg[(jy + 1) * 4 + jx] + xf[jx] * Pg[(jy + 1) * 4 + jx + 1]);
                        float cf = yg[jy] * (xg[jx] * Pf[jy * 4 + jx] + xf[jx] * Pf[jy * 4 + jx + 1])
                                 + yf[jy] * (xg[jx] * Pf[(jy + 1) * 4 + jx] + xf[jx] * Pf[(jy + 1) * 4 + jx + 1]);
                        float s = zg[jz] * cg + zf[jz] * cf;
                        s += __shfl_xor(s, 1);
                        if (hf == 0) {
                            int j = jz * 9 + jy * 3 + jx;
                            s_sc[j * 128 + qi] = s * SCALEc + brow[j];
                        }
                    }
            }
        }
        __syncthreads();

        // softmax stats over 27
        float m = -1e30f;
#pragma unroll
        for (int j = 0; j < 27; ++j) m = fmaxf(m, s_sc[j * 128 + qi]);
        float ssum = 0.f;
#pragma unroll
        for (int j = 0; j < 27; ++j) ssum += expf(s_sc[j * 128 + qi] - m);
        const float inv = 1.f / ssum;

        // pass 2: accumulate per-corner weights, then 64 weighted axpys
        float4 acc[4] = {};
#pragma unroll
        for (int tz = 0; tz < 4; ++tz) {
            float W[16] = {};
#pragma unroll
            for (int jz = 0; jz < 3; ++jz) {
                if (jz == tz || jz + 1 == tz) {
                    float wz = (jz == tz) ? zg[jz] : zf[jz];
#pragma unroll
                    for (int jy = 0; jy < 3; ++jy)
#pragma unroll
                        for (int jx = 0; jx < 3; ++jx) {
                            float aj = expf(s_sc[(jz * 9 + jy * 3 + jx) * 128 + qi] - m) * inv;
                            float a = aj * wz;
                            W[jy * 4 + jx]           += a * yg[jy] * xg[jx];
                            W[jy * 4 + jx + 1]       += a * yg[jy] * xf[jx];
                            W[(jy + 1) * 4 + jx]     += a * yf[jy] * xg[jx];
                            W[(jy + 1) * 4 + jx + 1] += a * yf[jy] * xf[jx];
                        }
                }
            }
#pragma unroll
            for (int ty = 0; ty < 4; ++ty)
#pragma unroll
                for (int tx = 0; tx < 4; ++tx)
                    axpy16(acc, W[ty * 4 + tx], vb + czo[tz] + cyo[ty] + cxo[tx]);
        }

        // epilogue: write o + lepe, |o| partial
        float* dst = ol + ((size_t)(b * Cc + h * HDc + hf * 16)) * Nn + n;
        float sabs = 0.f;
#pragma unroll
        for (int i = 0; i < 4; ++i) {
            float o0 = acc[i].x, o1 = acc[i].y, o2 = acc[i].z, o3 = acc[i].w;
            sabs += fabsf(o0) + fabsf(o1) + fabsf(o2) + fabsf(o3);
            size_t i0 = (size_t)(4 * i + 0) * Nn, i1 = (size_t)(4 * i + 1) * Nn;
            size_t i2 = (size_t)(4 * i + 2) * Nn, i3 = (size_t)(4 * i + 3) * Nn;
            dst[i0] = o0 + dst[i0];
            dst[i1] = o1 + dst[i1];
            dst[i2] = o2 + dst[i2];
            dst[i3] = o3 + dst[i3];
        }
#pragma unroll
        for (int o = 32; o > 0; o >>= 1) sabs += __shfl_down(sabs, o, 64);
        if ((tid & 63) == 0) s_red[tid >> 6] = sabs;
        __syncthreads();
        if (tid == 0) pe[wid] = s_red[0] + s_red[1] + s_red[2] + s_red[3];
        return;
    }

    // ---------------- dil=2: generic 27x8 path (no structural dedup) ----
    for (int jz = 0; jz < 3; ++jz) {
        int z0 = zi0[jz], z1 = zi1[jz];
        float zfv = zf[jz], zgv = zg[jz];
#pragma unroll
        for (int jy = 0; jy < 3; ++jy) {
#pragma unroll
            for (int jx = 0; jx < 3; ++jx) {
                float d00 = xg[jx] * dot16(qr, kb + z0 + yi0[jy] + xi0[jx])
                          + xf[jx] * dot16(qr, kb + z0 + yi0[jy] + xi1[jx]);
                float d01 = xg[jx] * dot16(qr, kb + z0 + yi1[jy] + xi0[jx])
                          + xf[jx] * dot16(qr, kb + z0 + yi1[jy] + xi1[jx]);
                float d10 = xg[jx] * dot16(qr, kb + z1 + yi0[jy] + xi0[jx])
                          + xf[jx] * dot16(qr, kb + z1 + yi0[jy] + xi1[jx]);
                float d11 = xg[jx] * dot16(qr, kb + z1 + yi1[jy] + xi0[jx])
                          + xf[jx] * dot16(qr, kb + z1 + yi1[jy] + xi1[jx]);
                float s = zgv * (yg[jy] * d00 + yf[jy] * d01)
                        + zfv * (yg[jy] * d10 + yf[jy] * d11);
                s += __shfl_xor(s, 1);
                if (hf == 0) {
                    int j = jz * 9 + jy * 3 + jx;
                    s_sc[j * 128 + qi] = s * SCALEc + brow[j];
                }
            }
        }
    }
    __syncthreads();

    float m = -1e30f;
#pragma unroll
    for (int j = 0; j < 27; ++j) m = fmaxf(m, s_sc[j * 128 + qi]);
    float ssum = 0.f;
#pragma unroll
    for (int j = 0; j < 27; ++j) ssum += expf(s_sc[j * 128 + qi] - m);
    const float inv = 1.f / ssum;

    float4 acc[4] = {};
    for (int jz = 0; jz < 3; ++jz) {
        int z0 = zi0[jz], z1 = zi1[jz];
        float zfv = zf[jz], zgv = zg[jz];
#pragma unroll
        for (int jy = 0; jy < 3; ++jy) {
#pragma unroll
            for (int jx = 0; jx < 3; ++jx) {
                int j = jz * 9 + jy * 3 + jx;
                float aj = expf(s_sc[j * 128 + qi] - m) * inv;
                float wz0 = aj * zgv, wz1 = aj * zfv;
                float w00 = wz0 * yg[jy], w01 = wz0 * yf[jy];
                float w10 = wz1 * yg[jy], w11 = wz1 * yf[jy];
                axpy16(acc, w00 * xg[jx], vb + z0 + yi0[jy] + xi0[jx]);
                axpy16(acc, w00 * xf[jx], vb + z0 + yi0[jy] + xi1[jx]);
                axpy16(acc, w01 * xg[jx], vb + z0 + yi1[jy] + xi0[jx]);
                axpy16(acc, w01 * xf[jx], vb + z0 + yi1[jy] + xi1[jx]);
                axpy16(acc, w10 * xg[jx], vb + z1 + yi0[jy] + xi0[jx]);
                axpy16(acc, w10 * xf[jx], vb + z1 + yi0[jy] + xi1[jx]);
                axpy16(acc, w11 * xg[jx], vb + z1 + yi1[jy] + xi0[jx]);
                axpy16(acc, w11 * xf[jx], vb + z1 + yi1[jy] + xi1[jx]);
            }
        }
    }

    float* dst = ol + ((size_t)(b * Cc + h * HDc + hf * 16)) * Nn + n;
    float sabs = 0.f;
#pragma unroll
    for (int i = 0; i < 4; ++i) {
        float o0 = acc[i].x, o1 = acc[i].y, o2 = acc[i].z, o3 = acc[i].w;
        sabs += fabsf(o0) + fabsf(o1) + fabsf(o2) + fabsf(o3);
        size_t i0 = (size_t)(4 * i + 0) * Nn, i1 = (size_t)(4 * i + 1) * Nn;
        size_t i2 = (size_t)(4 * i + 2) * Nn, i3 = (size_t)(4 * i + 3) * Nn;
        dst[i0] = o0 + dst[i0];
        dst[i1] = o1 + dst[i1];
        dst[i2] = o2 + dst[i2];
        dst[i3] = o3 + dst[i3];
    }
#pragma unroll
    for (int o = 32; o > 0; o >>= 1) sabs += __shfl_down(sabs, o, 64);
    if ((tid & 63) == 0) s_red[tid >> 6] = sabs;
    __syncthreads();
    if (tid == 0) pe[wid] = s_red[0] + s_red[1] + s_red[2] + s_red[3];
}

// ---------------------------------------------------------------------------
// K5: final projection GEMM  out = pw @ ol + pb    (ol = o + lepe)
// ---------------------------------------------------------------------------
__global__ __launch_bounds__(256) void gemm_out(
    const float* __restrict__ ol,
    const float* __restrict__ pw, const float* __restrict__ pb,
    float* __restrict__ out)
{
    __shared__ float Wt[32][68];
    __shared__ float Xt[32][68];
    const int tid = threadIdx.x;
    const int RO = blockIdx.y * 64;           // 0..128
    const int CO = blockIdx.x * 64;
    const int b  = CO >> 14;
    const int n0 = CO & 16383;
    const size_t xoff = (size_t)b * Cc * Nn + n0;

    float acc[4][4] = {};
    const int ty = tid >> 4, tx = tid & 15;

    for (int k0 = 0; k0 < 192; k0 += 32) {
#pragma unroll
        for (int i = 0; i < 2; ++i) {
            int li = tid + i * 256;
            int row = li >> 3;
            int kq = (li & 7) * 4;
            float4 wv = *(const float4*)(pw + (size_t)(RO + row) * 192 + k0 + kq);
            Wt[kq + 0][row] = wv.x; Wt[kq + 1][row] = wv.y;
            Wt[kq + 2][row] = wv.z; Wt[kq + 3][row] = wv.w;
        }
#pragma unroll
        for (int i = 0; i < 2; ++i) {
            int li = tid + i * 256;
            int kk = li >> 4;
            int c4 = (li & 15) * 4;
            float4 xv = *(const float4*)(ol + xoff + (size_t)(k0 + kk) * Nn + c4);
            *(float4*)&Xt[kk][c4] = xv;
        }
        __syncthreads();
#pragma unroll
        for (int kk = 0; kk < 32; ++kk) {
            float4 av = *(const float4*)&Wt[kk][ty * 4];
            float4 bv = *(const float4*)&Xt[kk][tx * 4];
            acc[0][0] += av.x * bv.x; acc[0][1] += av.x * bv.y; acc[0][2] += av.x * bv.z; acc[0][3] += av.x * bv.w;
            acc[1][0] += av.y * bv.x; acc[1][1] += av.y * bv.y; acc[1][2] += av.y * bv.z; acc[1][3] += av.y * bv.w;
            acc[2][0] += av.z * bv.x; acc[2][1] += av.z * bv.y; acc[2][2] += av.z * bv.z; acc[2][3] += av.z * bv.w;
            acc[3][0] += av.w * bv.x; acc[3][1] += av.w * bv.y; acc[3][2] += av.w * bv.z; acc[3][3] += av.w * bv.w;
        }
        __syncthreads();
    }
#pragma unroll
    for (int i = 0; i < 4; ++i) {
        int r = RO + ty * 4 + i;
        float bias = pb[r];
#pragma unroll
        for (int j = 0; j < 4; ++j) {
            out[((size_t)(b * Cc + r)) * Nn + n0 + tx * 4 + j] = acc[i][j] + bias;
        }
    }
}

// ---------------------------------------------------------------------------
// Reductions
// ---------------------------------------------------------------------------
__global__ __launch_bounds__(256) void mag_stage1(const float* __restrict__ offs, float* __restrict__ pm) {
    __shared__ float sm[4];
    int g = blockIdx.x >> 3, chunk = blockIdx.x & 7;   // g = bh (0..11)
    int tid = threadIdx.x;
    float s = 0.f;
    for (int i = tid; i < 2048; i += 256) {
        size_t base = ((size_t)g * Nn + chunk * 2048 + i) * 3;
        float a = offs[base], b = offs[base + 1], c = offs[base + 2];
        s += sqrtf(a * a + b * b + c * c);
    }
#pragma unroll
    for (int o = 32; o > 0; o >>= 1) s += __shfl_down(s, o, 64);
    if ((tid & 63) == 0) sm[tid >> 6] = s;
    __syncthreads();
    if (tid == 0) pm[blockIdx.x] = sm[0] + sm[1] + sm[2] + sm[3];
}

__global__ __launch_bounds__(64) void finalize_k(const float* __restrict__ pm, const float* __restrict__ pe,
                                                 float* __restrict__ out) {
    int tid = threadIdx.x;
    if (tid < 12) {
        float s = 0.f;
#pragma unroll
        for (int i = 0; i < 8; ++i) s += pm[tid * 8 + i];
        float mag = s / 16384.f;
        out[OUT_MAG + tid] = mag;
        int b = tid / 6, h = tid % 6;
        out[OUT_GUIDE + b * 8 + h] = mag;
    }
    if (tid < 4) {
        int b = tid >> 1, br = tid & 1;
        float s = 0.f;
        for (int hh = 0; hh < 3; ++hh)
            for (int c = 0; c < 128; ++c)
                s += pe[((b * NHc) + br * 3 + hh) * 128 + c];
        float e = s / 1572864.f;     // 3 heads * 32 dims * 16384 positions
        out[OUT_EN + tid] = e;
        out[OUT_GUIDE + b * 8 + 6 + br] = e;
    }
}

// ---------------------------------------------------------------------------
extern "C" void kernel_launch(void* const* d_in, const int* in_sizes, int n_in,
                              void* d_out, int out_size, void* d_ws, size_t ws_size,
                              hipStream_t stream) {
    const float* x    = (const float*)d_in[0];
    const float* qw   = (const float*)d_in[1];
    const float* qb   = (const float*)d_in[2];
    const float* kw   = (const float*)d_in[3];
    const float* kb   = (const float*)d_in[4];
    const float* vw   = (const float*)d_in[5];
    const float* vb   = (const float*)d_in[6];
    const float* pw   = (const float*)d_in[7];
    const float* pb   = (const float*)d_in[8];
    const float* odw  = (const float*)d_in[9];
    const float* odb  = (const float*)d_in[10];
    const float* lnw  = (const float*)d_in[11];
    const float* lnb  = (const float*)d_in[12];
    const float* opw  = (const float*)d_in[13];
    const float* opb  = (const float*)d_in[14];
    const float* rpew = (const float*)d_in[15];
    const float* rpeb = (const float*)d_in[16];
    const float* bias0 = (const float*)d_in[17];
    const float* bias1 = (const float*)d_in[18];

    float* ws = (float*)d_ws;
    float* q_p  = ws;                            // BIG
    float* k_t  = ws + (size_t)BIG;              // BIG
    float* v_t  = ws + (size_t)2 * BIG;          // BIG
    float* ol   = ws + (size_t)3 * BIG;          // BIG (lepe, then o+lepe)
    float* t_dw = ws + (size_t)4 * BIG;          // BIG
    float* t3   = ws + (size_t)5 * BIG;          // 589824
    float* pm   = t3 + 589824;                   // 96
    float* pe   = pm + 96;                       // 1536

    float* out = (float*)d_out;
    float* offs_out = out + OUT_OFFS;

    gemm_qkv<<<dim3(512, 9), 256, 0, stream>>>(x, qw, qb, kw, kb, vw, vb, q_p, k_t, v_t);
    dwconv2<<<24576, 256, 0, stream>>>(q_p, rpew, rpeb, odw, odb, ol, t_dw);
    ln_offs<<<512, 256, 0, stream>>>(t_dw, lnw, lnb, opw, opb, t3, offs_out);
    attn_kernel<<<1536, 256, 0, stream>>>(q_p, k_t, v_t, t3, bias0, bias1, ol, pe);
    gemm_out<<<dim3(512, 3), 256, 0, stream>>>(ol, pw, pb, out);
    mag_stage1<<<96, 256, 0, stream>>>(offs_out, pm);
    finalize_k<<<1, 64, 0, stream>>>(pm, pe, out);
}

// Round 8
// 973.797 us; speedup vs baseline: 1.1347x; 1.1347x over previous
//
#include <hip/hip_runtime.h>
#include <hip/hip_bf16.h>

// Problem constants
#define Bc   2
#define Cc   192
#define NHc  6
#define HDc  32
#define Dd   16
#define Hh   32
#define Ww   32
#define Nn   16384          // Dd*Hh*Ww
#define SCALEc 0.17677669529663687f   // 32^-0.5

// d_out layout (floats):
//   out        [B,192,N]      @ 0          (6291456)
//   offs       [B,6,N,3]      @ 6291456    (589824)
//   offset_mag [B,6]          @ 6881280    (12)
//   branch_en  [B,2]          @ 6881292    (4)
//   guide      [B,8]          @ 6881296    (16)
#define OUT_OFFS   6291456
#define OUT_MAG    6881280
#define OUT_EN     6881292
#define OUT_GUIDE  6881296

#define BIG 6291456   // B*C*N floats
// ws layout (floats): q_p @0, k_t @BIG, v_t @2BIG, ol(lepe->o+lepe) @3BIG,
//                     t_dw @4BIG, t3 @5BIG (589824), pm (96), pe (1536)

// ---------------------------------------------------------------------------
// K1: fused QKV projection GEMM.  rows 0..575 = [qw;kw;vw] @ x  (+bias)
// q -> planar [b,c,n];  k,v -> transposed [bh,n,32]
// ---------------------------------------------------------------------------
__global__ __launch_bounds__(256) void gemm_qkv(
    const float* __restrict__ x,
    const float* __restrict__ qw, const float* __restrict__ qb,
    const float* __restrict__ kw, const float* __restrict__ kb,
    const float* __restrict__ vw, const float* __restrict__ vb,
    float* __restrict__ q_p, float* __restrict__ k_t, float* __restrict__ v_t)
{
    __shared__ float Wt[32][68];   // [kk][row]
    __shared__ float Xt[32][68];   // [kk][col]
    const int tid = threadIdx.x;
    const int RO = blockIdx.y * 64;           // 0..512
    const int CO = blockIdx.x * 64;           // 0..32704
    const int b  = CO >> 14;
    const int n0 = CO & 16383;
    const int proj = RO / 192;
    const int wr0  = RO % 192;
    const float* wsel = (proj == 0) ? qw : (proj == 1) ? kw : vw;
    const float* bsel = (proj == 0) ? qb : (proj == 1) ? kb : vb;
    const float* xb = x + (size_t)b * Cc * Nn;

    float acc[4][4] = {};
    const int ty = tid >> 4, tx = tid & 15;

    for (int k0 = 0; k0 < 192; k0 += 32) {
#pragma unroll
        for (int i = 0; i < 2; ++i) {         // W tile: 64 rows x 32 k
            int li = tid + i * 256;
            int row = li >> 3;
            int kq = (li & 7) * 4;
            float4 wv = *(const float4*)(wsel + (size_t)(wr0 + row) * 192 + k0 + kq);
            Wt[kq + 0][row] = wv.x; Wt[kq + 1][row] = wv.y;
            Wt[kq + 2][row] = wv.z; Wt[kq + 3][row] = wv.w;
        }
#pragma unroll
        for (int i = 0; i < 2; ++i) {         // X tile: 32 k x 64 cols
            int li = tid + i * 256;
            int kk = li >> 4;
            int c4 = (li & 15) * 4;
            float4 xv = *(const float4*)(xb + (size_t)(k0 + kk) * Nn + n0 + c4);
            *(float4*)&Xt[kk][c4] = xv;
        }
        __syncthreads();
#pragma unroll
        for (int kk = 0; kk < 32; ++kk) {
            float4 av = *(const float4*)&Wt[kk][ty * 4];
            float4 bv = *(const float4*)&Xt[kk][tx * 4];
            acc[0][0] += av.x * bv.x; acc[0][1] += av.x * bv.y; acc[0][2] += av.x * bv.z; acc[0][3] += av.x * bv.w;
            acc[1][0] += av.y * bv.x; acc[1][1] += av.y * bv.y; acc[1][2] += av.y * bv.z; acc[1][3] += av.y * bv.w;
            acc[2][0] += av.z * bv.x; acc[2][1] += av.z * bv.y; acc[2][2] += av.z * bv.z; acc[2][3] += av.z * bv.w;
            acc[3][0] += av.w * bv.x; acc[3][1] += av.w * bv.y; acc[3][2] += av.w * bv.z; acc[3][3] += av.w * bv.w;
        }
        __syncthreads();
    }

#pragma unroll
    for (int i = 0; i < 4; ++i) {
        int wr = wr0 + ty * 4 + i;
        float bias = bsel[wr];
        int hh = wr >> 5, dd = wr & 31;
#pragma unroll
        for (int j = 0; j < 4; ++j) {
            int n = n0 + tx * 4 + j;
            float v = acc[i][j] + bias;
            if (proj == 0) {
                q_p[((size_t)(b * Cc + wr)) * Nn + n] = v;
            } else {
                float* tdst = (proj == 1) ? k_t : v_t;
                tdst[((size_t)((b * NHc + hh) * Nn + n)) * HDc + dd] = v;
            }
        }
    }
}

// ---------------------------------------------------------------------------
// K2: two depthwise 3x3x3 convs (zero pad) over q: lepe (rpew) and t (odw)
// ---------------------------------------------------------------------------
__global__ __launch_bounds__(256) void dwconv2(
    const float* __restrict__ q_p,
    const float* __restrict__ rpew, const float* __restrict__ rpeb,
    const float* __restrict__ odw,  const float* __restrict__ odb,
    float* __restrict__ lepe, float* __restrict__ t_dw)
{
    int idx = blockIdx.x * 256 + threadIdx.x;     // < 6291456
    int n = idx & 16383;
    int bc = idx >> 14;
    int c = bc % Cc;
    int x = n & 31, y = (n >> 5) & 31, z = n >> 10;
    const float* src = q_p + (size_t)bc * Nn;
    float a1 = 0.f, a2 = 0.f;
#pragma unroll
    for (int kz = 0; kz < 3; ++kz) {
        int zz = z + kz - 1; bool zok = ((unsigned)zz < (unsigned)Dd);
#pragma unroll
        for (int ky = 0; ky < 3; ++ky) {
            int yy = y + ky - 1; bool yok = ((unsigned)yy < (unsigned)Hh);
#pragma unroll
            for (int kx = 0; kx < 3; ++kx) {
                int xx = x + kx - 1; bool xok = ((unsigned)xx < (unsigned)Ww);
                if (zok && yok && xok) {
                    float v = src[(zz * 32 + yy) * 32 + xx];
                    int wi = c * 27 + kz * 9 + ky * 3 + kx;
                    a1 += rpew[wi] * v;
                    a2 += odw[wi] * v;
                }
            }
        }
    }
    lepe[idx] = a1 + rpeb[c];
    t_dw[idx] = a2 + odb[c];
}

// ---------------------------------------------------------------------------
// K3: channel-LN + exact GeLU + 18-row offset projection + tanh
// ---------------------------------------------------------------------------
__global__ __launch_bounds__(256) void ln_offs(
    const float* __restrict__ t_dw,
    const float* __restrict__ lnw, const float* __restrict__ lnb,
    const float* __restrict__ opw, const float* __restrict__ opb,
    float* __restrict__ t3, float* __restrict__ offs_out)
{
    __shared__ float s_stat[2][4][64];
    __shared__ float s_acc[4][18][64];
    const int tid = threadIdx.x;
    const int p = tid >> 6;          // channel part 0..3
    const int l = tid & 63;          // position within block
    const int gb = blockIdx.x;       // 0..511
    const int b = gb >> 8;
    const int n = (gb & 255) * 64 + l;
    const float* src = t_dw + (size_t)b * Cc * Nn + n;

    float s = 0.f, s2 = 0.f;
    for (int c = p * 48; c < p * 48 + 48; ++c) {
        float v = src[(size_t)c * Nn];
        s += v; s2 += v * v;
    }
    s_stat[0][p][l] = s; s_stat[1][p][l] = s2;
    __syncthreads();
    float st  = s_stat[0][0][l] + s_stat[0][1][l] + s_stat[0][2][l] + s_stat[0][3][l];
    float st2 = s_stat[1][0][l] + s_stat[1][1][l] + s_stat[1][2][l] + s_stat[1][3][l];
    float mean = st * (1.f / 192.f);
    float var  = st2 * (1.f / 192.f) - mean * mean;
    float rstd = rsqrtf(var + 1e-5f);

    float acc[18] = {};
    for (int c = p * 48; c < p * 48 + 48; ++c) {
        float v = src[(size_t)c * Nn];
        float xn = (v - mean) * rstd;
        float yv = xn * lnw[c] + lnb[c];
        float g = 0.5f * yv * (1.f + erff(yv * 0.70710678118654752f));
#pragma unroll
        for (int r = 0; r < 18; ++r) acc[r] += opw[r * 192 + c] * g;
    }
#pragma unroll
    for (int r = 0; r < 18; ++r) s_acc[p][r][l] = acc[r];
    __syncthreads();

    if (p < 3) {
#pragma unroll
        for (int hp = 0; hp < 2; ++hp) {
            int hh = p * 2 + hp;
            size_t base = ((size_t)((b * NHc + hh) * Nn) + n) * 3;
#pragma unroll
            for (int i = 0; i < 3; ++i) {
                int r = hh * 3 + i;
                float v = s_acc[0][r][l] + s_acc[1][r][l] + s_acc[2][r][l] + s_acc[3][r][l] + opb[r];
                float t = tanhf(v);
                float sc = (i == 2) ? (2.f / 15.f) : (2.f / 31.f);
                t3[base + i] = t;
                offs_out[base + i] = t * sc;
            }
        }
    }
}

// ---------------------------------------------------------------------------
// K4: deformable attention v4 — corner dedup with straight-line planes
// (named arrays, compile-time indices only => no scratch; rule #20 fix)
// ---------------------------------------------------------------------------
__device__ __forceinline__ float dot16(const float4* q4, const float* r) {
    const float4* r4 = (const float4*)r;
    float s = 0.f;
#pragma unroll
    for (int i = 0; i < 4; ++i) {
        float4 a = q4[i], b = r4[i];
        s += a.x * b.x + a.y * b.y + a.z * b.z + a.w * b.w;
    }
    return s;
}

__device__ __forceinline__ void axpy16(float4* acc, float w, const float* r) {
    const float4* r4 = (const float4*)r;
#pragma unroll
    for (int i = 0; i < 4; ++i) {
        float4 b = r4[i];
        acc[i].x += w * b.x; acc[i].y += w * b.y;
        acc[i].z += w * b.z; acc[i].w += w * b.w;
    }
}

// load one z-plane of 16 corner dots (static indices only)
#define LOADPL(P, CZO) do {                                                   \
    _Pragma("unroll")                                                         \
    for (int t = 0; t < 16; ++t)                                              \
        P[t] = dot16(qr, kb + (CZO) + cyo[t >> 2] + cxo[t & 3]);              \
} while (0)

// emit 9 scores for sample-plane JZ from corner planes Pg (z=jz) / Pf (z=jz+1)
#define EMITJZ(JZ, Pg, Pf) do {                                               \
    _Pragma("unroll")                                                         \
    for (int jy = 0; jy < 3; ++jy) {                                          \
        _Pragma("unroll")                                                     \
        for (int jx = 0; jx < 3; ++jx) {                                      \
            float cg = yg[jy] * (xg[jx] * Pg[jy*4+jx]     + xf[jx] * Pg[jy*4+jx+1])    \
                     + yf[jy] * (xg[jx] * Pg[(jy+1)*4+jx] + xf[jx] * Pg[(jy+1)*4+jx+1]); \
            float cf = yg[jy] * (xg[jx] * Pf[jy*4+jx]     + xf[jx] * Pf[jy*4+jx+1])    \
                     + yf[jy] * (xg[jx] * Pf[(jy+1)*4+jx] + xf[jx] * Pf[(jy+1)*4+jx+1]); \
            float s = zg[JZ] * cg + zf[JZ] * cf;                              \
            s += __shfl_xor(s, 1);                                            \
            if (hf == 0) {                                                    \
                s_sc[((JZ)*9 + jy*3 + jx) * 128 + qi] = s * SCALEc + brow[(JZ)*9 + jy*3 + jx]; \
            }                                                                 \
        }                                                                     \
    }                                                                         \
} while (0)

// accumulate sample-plane JZ's weights (z-weight WZ) into corner-plane W[16]
#define ADDW(W, JZ, WZ) do {                                                  \
    _Pragma("unroll")                                                         \
    for (int jy = 0; jy < 3; ++jy) {                                          \
        _Pragma("unroll")                                                     \
        for (int jx = 0; jx < 3; ++jx) {                                      \
            float aj = expf(s_sc[((JZ)*9+jy*3+jx)*128+qi] - m) * inv * (WZ);  \
            W[jy*4+jx]         += aj * yg[jy] * xg[jx];                       \
            W[jy*4+jx+1]       += aj * yg[jy] * xf[jx];                       \
            W[(jy+1)*4+jx]     += aj * yf[jy] * xg[jx];                       \
            W[(jy+1)*4+jx+1]   += aj * yf[jy] * xf[jx];                       \
        }                                                                     \
    }                                                                         \
} while (0)

#define AXPYPL(W, CZO) do {                                                   \
    _Pragma("unroll")                                                         \
    for (int t = 0; t < 16; ++t)                                              \
        axpy16(acc, W[t], vb + (CZO) + cyo[t >> 2] + cxo[t & 3]);             \
} while (0)

__global__ __launch_bounds__(256, 2) void attn_kernel(
    const float* __restrict__ q_p, const float* __restrict__ k_t,
    const float* __restrict__ v_t, const float* __restrict__ t3,
    const float* __restrict__ bias0, const float* __restrict__ bias1,
    float* __restrict__ ol, float* __restrict__ pe)
{
    __shared__ float s_sc[27 * 128];   // raw scores, one slot per query
    __shared__ float s_red[4];
    const int tid = threadIdx.x;
    // XCD-aware bijective swizzle: 1536 = 8 * 192
    const int wid = (blockIdx.x & 7) * 192 + (blockIdx.x >> 3);
    const int bh = wid >> 7;           // 128 blocks per bh
    const int nt = wid & 127;
    const int qi = tid >> 1;           // query within block 0..127
    const int hf = tid & 1;            // head-dim half
    const int n = nt * 128 + qi;
    const int b = bh / NHc, h = bh % NHc;
    const int dil = (h < 3) ? 1 : 2;
    const float* brow = (h < 3) ? (bias0 + h * 27) : (bias1 + (h - 3) * 27);
    const int x = n & 31, y = (n >> 5) & 31, z = n >> 10;

    const float* t3p = t3 + ((size_t)bh * Nn + n) * 3;
    const float pxb = (float)x + t3p[0];
    const float pyb = (float)y + t3p[1];
    const float pzb = (float)z + t3p[2];

    // per-axis per-sample clamp/floor precompute (all three axes)
    int xi0[3], xi1[3]; float xf[3], xg[3];
    int yi0[3], yi1[3]; float yf[3], yg[3];
    int zi0[3], zi1[3]; float zf[3], zg[3];
#pragma unroll
    for (int jj = 0; jj < 3; ++jj) {
        float p = fminf(fmaxf(pxb + (float)((jj - 1) * dil), 0.f), 31.f);
        float f0 = floorf(p); int i0 = (int)f0;
        xi0[jj] = i0 * HDc; xi1[jj] = min(i0 + 1, 31) * HDc;
        xf[jj] = p - f0; xg[jj] = 1.f - xf[jj];
        p = fminf(fmaxf(pyb + (float)((jj - 1) * dil), 0.f), 31.f);
        f0 = floorf(p); i0 = (int)f0;
        yi0[jj] = i0 * (Ww * HDc); yi1[jj] = min(i0 + 1, 31) * (Ww * HDc);
        yf[jj] = p - f0; yg[jj] = 1.f - yf[jj];
        p = fminf(fmaxf(pzb + (float)((jj - 1) * dil), 0.f), 15.f);
        f0 = floorf(p); i0 = (int)f0;
        zi0[jj] = i0 * (Hh * Ww * HDc); zi1[jj] = min(i0 + 1, 15) * (Hh * Ww * HDc);
        zf[jj] = p - f0; zg[jj] = 1.f - zf[jj];
    }

    // q half (16 dims) from planar layout: coalesced strided loads
    float4 qr[4];
    {
        const float* qsrc = q_p + ((size_t)(b * Cc + h * HDc + hf * 16)) * Nn + n;
#pragma unroll
        for (int i = 0; i < 4; ++i) {
            qr[i].x = qsrc[(size_t)(4 * i + 0) * Nn];
            qr[i].y = qsrc[(size_t)(4 * i + 1) * Nn];
            qr[i].z = qsrc[(size_t)(4 * i + 2) * Nn];
            qr[i].w = qsrc[(size_t)(4 * i + 3) * Nn];
        }
    }
    const float* kb = k_t + (size_t)bh * Nn * HDc + hf * 16;
    const float* vb = v_t + (size_t)bh * Nn * HDc + hf * 16;

    if (h < 3) {
        // ---------------- dil=1: 4x4x4 corner-dedup path ----------------
        // corner lists; exact under clamping (mismatched corners have w=0)
        const int cxo[4] = { xi0[0], xi0[1], xi0[2], xi1[2] };
        const int cyo[4] = { yi0[0], yi0[1], yi0[2], yi1[2] };
        const int czo0 = zi0[0], czo1 = zi0[1], czo2 = zi0[2], czo3 = zi1[2];

        // pass 1: straight-line rolling planes (named arrays, no aliasing)
        float plA[16], plB[16];
        LOADPL(plA, czo0);             // corner plane 0
        LOADPL(plB, czo1);             // corner plane 1
        EMITJZ(0, plA, plB);
        LOADPL(plA, czo2);             // corner plane 2 (overwrites 0)
        EMITJZ(1, plB, plA);
        LOADPL(plB, czo3);             // corner plane 3 (overwrites 1)
        EMITJZ(2, plA, plB);
        __syncthreads();

        // softmax stats over 27
        float m = -1e30f;
#pragma unroll
        for (int j = 0; j < 27; ++j) m = fmaxf(m, s_sc[j * 128 + qi]);
        float ssum = 0.f;
#pragma unroll
        for (int j = 0; j < 27; ++j) ssum += expf(s_sc[j * 128 + qi] - m);
        const float inv = 1.f / ssum;

        // pass 2: per-corner-plane weights, straight-line
        float4 acc[4] = {};
        {
            float W[16] = {};
            ADDW(W, 0, zg[0]);
            AXPYPL(W, czo0);
        }
        {
            float W[16] = {};
            ADDW(W, 0, zf[0]);
            ADDW(W, 1, zg[1]);
            AXPYPL(W, czo1);
        }
        {
            float W[16] = {};
            ADDW(W, 1, zf[1]);
            ADDW(W, 2, zg[2]);
            AXPYPL(W, czo2);
        }
        {
            float W[16] = {};
            ADDW(W, 2, zf[2]);
            AXPYPL(W, czo3);
        }

        // epilogue: write o + lepe, |o| partial
        float* dst = ol + ((size_t)(b * Cc + h * HDc + hf * 16)) * Nn + n;
        float sabs = 0.f;
#pragma unroll
        for (int i = 0; i < 4; ++i) {
            float o0 = acc[i].x, o1 = acc[i].y, o2 = acc[i].z, o3 = acc[i].w;
            sabs += fabsf(o0) + fabsf(o1) + fabsf(o2) + fabsf(o3);
            size_t i0 = (size_t)(4 * i + 0) * Nn, i1 = (size_t)(4 * i + 1) * Nn;
            size_t i2 = (size_t)(4 * i + 2) * Nn, i3 = (size_t)(4 * i + 3) * Nn;
            dst[i0] = o0 + dst[i0];
            dst[i1] = o1 + dst[i1];
            dst[i2] = o2 + dst[i2];
            dst[i3] = o3 + dst[i3];
        }
#pragma unroll
        for (int o = 32; o > 0; o >>= 1) sabs += __shfl_down(sabs, o, 64);
        if ((tid & 63) == 0) s_red[tid >> 6] = sabs;
        __syncthreads();
        if (tid == 0) pe[wid] = s_red[0] + s_red[1] + s_red[2] + s_red[3];
        return;
    }

    // ---------------- dil=2: generic 27x8 path (no structural dedup) ----
    for (int jz = 0; jz < 3; ++jz) {
        int z0 = zi0[jz], z1 = zi1[jz];
        float zfv = zf[jz], zgv = zg[jz];
#pragma unroll
        for (int jy = 0; jy < 3; ++jy) {
#pragma unroll
            for (int jx = 0; jx < 3; ++jx) {
                float d00 = xg[jx] * dot16(qr, kb + z0 + yi0[jy] + xi0[jx])
                          + xf[jx] * dot16(qr, kb + z0 + yi0[jy] + xi1[jx]);
                float d01 = xg[jx] * dot16(qr, kb + z0 + yi1[jy] + xi0[jx])
                          + xf[jx] * dot16(qr, kb + z0 + yi1[jy] + xi1[jx]);
                float d10 = xg[jx] * dot16(qr, kb + z1 + yi0[jy] + xi0[jx])
                          + xf[jx] * dot16(qr, kb + z1 + yi0[jy] + xi1[jx]);
                float d11 = xg[jx] * dot16(qr, kb + z1 + yi1[jy] + xi0[jx])
                          + xf[jx] * dot16(qr, kb + z1 + yi1[jy] + xi1[jx]);
                float s = zgv * (yg[jy] * d00 + yf[jy] * d01)
                        + zfv * (yg[jy] * d10 + yf[jy] * d11);
                s += __shfl_xor(s, 1);
                if (hf == 0) {
                    int j = jz * 9 + jy * 3 + jx;
                    s_sc[j * 128 + qi] = s * SCALEc + brow[j];
                }
            }
        }
    }
    __syncthreads();

    float m = -1e30f;
#pragma unroll
    for (int j = 0; j < 27; ++j) m = fmaxf(m, s_sc[j * 128 + qi]);
    float ssum = 0.f;
#pragma unroll
    for (int j = 0; j < 27; ++j) ssum += expf(s_sc[j * 128 + qi] - m);
    const float inv = 1.f / ssum;

    float4 acc[4] = {};
    for (int jz = 0; jz < 3; ++jz) {
        int z0 = zi0[jz], z1 = zi1[jz];
        float zfv = zf[jz], zgv = zg[jz];
#pragma unroll
        for (int jy = 0; jy < 3; ++jy) {
#pragma unroll
            for (int jx = 0; jx < 3; ++jx) {
                int j = jz * 9 + jy * 3 + jx;
                float aj = expf(s_sc[j * 128 + qi] - m) * inv;
                float wz0 = aj * zgv, wz1 = aj * zfv;
                float w00 = wz0 * yg[jy], w01 = wz0 * yf[jy];
                float w10 = wz1 * yg[jy], w11 = wz1 * yf[jy];
                axpy16(acc, w00 * xg[jx], vb + z0 + yi0[jy] + xi0[jx]);
                axpy16(acc, w00 * xf[jx], vb + z0 + yi0[jy] + xi1[jx]);
                axpy16(acc, w01 * xg[jx], vb + z0 + yi1[jy] + xi0[jx]);
                axpy16(acc, w01 * xf[jx], vb + z0 + yi1[jy] + xi1[jx]);
                axpy16(acc, w10 * xg[jx], vb + z1 + yi0[jy] + xi0[jx]);
                axpy16(acc, w10 * xf[jx], vb + z1 + yi0[jy] + xi1[jx]);
                axpy16(acc, w11 * xg[jx], vb + z1 + yi1[jy] + xi0[jx]);
                axpy16(acc, w11 * xf[jx], vb + z1 + yi1[jy] + xi1[jx]);
            }
        }
    }

    float* dst = ol + ((size_t)(b * Cc + h * HDc + hf * 16)) * Nn + n;
    float sabs = 0.f;
#pragma unroll
    for (int i = 0; i < 4; ++i) {
        float o0 = acc[i].x, o1 = acc[i].y, o2 = acc[i].z, o3 = acc[i].w;
        sabs += fabsf(o0) + fabsf(o1) + fabsf(o2) + fabsf(o3);
        size_t i0 = (size_t)(4 * i + 0) * Nn, i1 = (size_t)(4 * i + 1) * Nn;
        size_t i2 = (size_t)(4 * i + 2) * Nn, i3 = (size_t)(4 * i + 3) * Nn;
        dst[i0] = o0 + dst[i0];
        dst[i1] = o1 + dst[i1];
        dst[i2] = o2 + dst[i2];
        dst[i3] = o3 + dst[i3];
    }
#pragma unroll
    for (int o = 32; o > 0; o >>= 1) sabs += __shfl_down(sabs, o, 64);
    if ((tid & 63) == 0) s_red[tid >> 6] = sabs;
    __syncthreads();
    if (tid == 0) pe[wid] = s_red[0] + s_red[1] + s_red[2] + s_red[3];
}

// ---------------------------------------------------------------------------
// K5: final projection GEMM  out = pw @ ol + pb    (ol = o + lepe)
// ---------------------------------------------------------------------------
__global__ __launch_bounds__(256) void gemm_out(
    const float* __restrict__ ol,
    const float* __restrict__ pw, const float* __restrict__ pb,
    float* __restrict__ out)
{
    __shared__ float Wt[32][68];
    __shared__ float Xt[32][68];
    const int tid = threadIdx.x;
    const int RO = blockIdx.y * 64;           // 0..128
    const int CO = blockIdx.x * 64;
    const int b  = CO >> 14;
    const int n0 = CO & 16383;
    const size_t xoff = (size_t)b * Cc * Nn + n0;

    float acc[4][4] = {};
    const int ty = tid >> 4, tx = tid & 15;

    for (int k0 = 0; k0 < 192; k0 += 32) {
#pragma unroll
        for (int i = 0; i < 2; ++i) {
            int li = tid + i * 256;
            int row = li >> 3;
            int kq = (li & 7) * 4;
            float4 wv = *(const float4*)(pw + (size_t)(RO + row) * 192 + k0 + kq);
            Wt[kq + 0][row] = wv.x; Wt[kq + 1][row] = wv.y;
            Wt[kq + 2][row] = wv.z; Wt[kq + 3][row] = wv.w;
        }
#pragma unroll
        for (int i = 0; i < 2; ++i) {
            int li = tid + i * 256;
            int kk = li >> 4;
            int c4 = (li & 15) * 4;
            float4 xv = *(const float4*)(ol + xoff + (size_t)(k0 + kk) * Nn + c4);
            *(float4*)&Xt[kk][c4] = xv;
        }
        __syncthreads();
#pragma unroll
        for (int kk = 0; kk < 32; ++kk) {
            float4 av = *(const float4*)&Wt[kk][ty * 4];
            float4 bv = *(const float4*)&Xt[kk][tx * 4];
            acc[0][0] += av.x * bv.x; acc[0][1] += av.x * bv.y; acc[0][2] += av.x * bv.z; acc[0][3] += av.x * bv.w;
            acc[1][0] += av.y * bv.x; acc[1][1] += av.y * bv.y; acc[1][2] += av.y * bv.z; acc[1][3] += av.y * bv.w;
            acc[2][0] += av.z * bv.x; acc[2][1] += av.z * bv.y; acc[2][2] += av.z * bv.z; acc[2][3] += av.z * bv.w;
            acc[3][0] += av.w * bv.x; acc[3][1] += av.w * bv.y; acc[3][2] += av.w * bv.z; acc[3][3] += av.w * bv.w;
        }
        __syncthreads();
    }
#pragma unroll
    for (int i = 0; i < 4; ++i) {
        int r = RO + ty * 4 + i;
        float bias = pb[r];
#pragma unroll
        for (int j = 0; j < 4; ++j) {
            out[((size_t)(b * Cc + r)) * Nn + n0 + tx * 4 + j] = acc[i][j] + bias;
        }
    }
}

// ---------------------------------------------------------------------------
// Reductions
// ---------------------------------------------------------------------------
__global__ __launch_bounds__(256) void mag_stage1(const float* __restrict__ offs, float* __restrict__ pm) {
    __shared__ float sm[4];
    int g = blockIdx.x >> 3, chunk = blockIdx.x & 7;   // g = bh (0..11)
    int tid = threadIdx.x;
    float s = 0.f;
    for (int i = tid; i < 2048; i += 256) {
        size_t base = ((size_t)g * Nn + chunk * 2048 + i) * 3;
        float a = offs[base], b = offs[base + 1], c = offs[base + 2];
        s += sqrtf(a * a + b * b + c * c);
    }
#pragma unroll
    for (int o = 32; o > 0; o >>= 1) s += __shfl_down(s, o, 64);
    if ((tid & 63) == 0) sm[tid >> 6] = s;
    __syncthreads();
    if (tid == 0) pm[blockIdx.x] = sm[0] + sm[1] + sm[2] + sm[3];
}

__global__ __launch_bounds__(64) void finalize_k(const float* __restrict__ pm, const float* __restrict__ pe,
                                                 float* __restrict__ out) {
    int tid = threadIdx.x;
    if (tid < 12) {
        float s = 0.f;
#pragma unroll
        for (int i = 0; i < 8; ++i) s += pm[tid * 8 + i];
        float mag = s / 16384.f;
        out[OUT_MAG + tid] = mag;
        int b = tid / 6, h = tid % 6;
        out[OUT_GUIDE + b * 8 + h] = mag;
    }
    if (tid < 4) {
        int b = tid >> 1, br = tid & 1;
        float s = 0.f;
        for (int hh = 0; hh < 3; ++hh)
            for (int c = 0; c < 128; ++c)
                s += pe[((b * NHc) + br * 3 + hh) * 128 + c];
        float e = s / 1572864.f;     // 3 heads * 32 dims * 16384 positions
        out[OUT_EN + tid] = e;
        out[OUT_GUIDE + b * 8 + 6 + br] = e;
    }
}

// ---------------------------------------------------------------------------
extern "C" void kernel_launch(void* const* d_in, const int* in_sizes, int n_in,
                              void* d_out, int out_size, void* d_ws, size_t ws_size,
                              hipStream_t stream) {
    const float* x    = (const float*)d_in[0];
    const float* qw   = (const float*)d_in[1];
    const float* qb   = (const float*)d_in[2];
    const float* kw   = (const float*)d_in[3];
    const float* kb   = (const float*)d_in[4];
    const float* vw   = (const float*)d_in[5];
    const float* vb   = (const float*)d_in[6];
    const float* pw   = (const float*)d_in[7];
    const float* pb   = (const float*)d_in[8];
    const float* odw  = (const float*)d_in[9];
    const float* odb  = (const float*)d_in[10];
    const float* lnw  = (const float*)d_in[11];
    const float* lnb  = (const float*)d_in[12];
    const float* opw  = (const float*)d_in[13];
    const float* opb  = (const float*)d_in[14];
    const float* rpew = (const float*)d_in[15];
    const float* rpeb = (const float*)d_in[16];
    const float* bias0 = (const float*)d_in[17];
    const float* bias1 = (const float*)d_in[18];

    float* ws = (float*)d_ws;
    float* q_p  = ws;                            // BIG
    float* k_t  = ws + (size_t)BIG;              // BIG
    float* v_t  = ws + (size_t)2 * BIG;          // BIG
    float* ol   = ws + (size_t)3 * BIG;          // BIG (lepe, then o+lepe)
    float* t_dw = ws + (size_t)4 * BIG;          // BIG
    float* t3   = ws + (size_t)5 * BIG;          // 589824
    float* pm   = t3 + 589824;                   // 96
    float* pe   = pm + 96;                       // 1536

    float* out = (float*)d_out;
    float* offs_out = out + OUT_OFFS;

    gemm_qkv<<<dim3(512, 9), 256, 0, stream>>>(x, qw, qb, kw, kb, vw, vb, q_p, k_t, v_t);
    dwconv2<<<24576, 256, 0, stream>>>(q_p, rpew, rpeb, odw, odb, ol, t_dw);
    ln_offs<<<512, 256, 0, stream>>>(t_dw, lnw, lnb, opw, opb, t3, offs_out);
    attn_kernel<<<1536, 256, 0, stream>>>(q_p, k_t, v_t, t3, bias0, bias1, ol, pe);
    gemm_out<<<dim3(512, 3), 256, 0, stream>>>(ol, pw, pb, out);
    mag_stage1<<<96, 256, 0, stream>>>(offs_out, pm);
    finalize_k<<<1, 64, 0, stream>>>(pm, pe, out);
}

// Round 9
// 949.163 us; speedup vs baseline: 1.1642x; 1.0260x over previous
//
#include <hip/hip_runtime.h>
#include <hip/hip_bf16.h>

// Problem constants
#define Bc   2
#define Cc   192
#define NHc  6
#define HDc  32
#define Dd   16
#define Hh   32
#define Ww   32
#define Nn   16384          // Dd*Hh*Ww
#define SCALEc 0.17677669529663687f   // 32^-0.5

// d_out layout (floats):
//   out        [B,192,N]      @ 0          (6291456)
//   offs       [B,6,N,3]      @ 6291456    (589824)
//   offset_mag [B,6]          @ 6881280    (12)
//   branch_en  [B,2]          @ 6881292    (4)
//   guide      [B,8]          @ 6881296    (16)
#define OUT_OFFS   6291456
#define OUT_MAG    6881280
#define OUT_EN     6881292
#define OUT_GUIDE  6881296

#define BIG 6291456   // B*C*N floats
// ws layout (floats): q_p @0, k_t @BIG, v_t @2BIG, ol(lepe->o+lepe) @3BIG,
//                     t_dw @4BIG, t3 @5BIG (589824), pm (96), pe (1536)

// ---------------------------------------------------------------------------
// K1: fused QKV projection GEMM.  rows 0..575 = [qw;kw;vw] @ x  (+bias)
// q -> planar [b,c,n];  k,v -> transposed [bh,n,32]
// ---------------------------------------------------------------------------
__global__ __launch_bounds__(256) void gemm_qkv(
    const float* __restrict__ x,
    const float* __restrict__ qw, const float* __restrict__ qb,
    const float* __restrict__ kw, const float* __restrict__ kb,
    const float* __restrict__ vw, const float* __restrict__ vb,
    float* __restrict__ q_p, float* __restrict__ k_t, float* __restrict__ v_t)
{
    __shared__ float Wt[32][68];   // [kk][row]
    __shared__ float Xt[32][68];   // [kk][col]
    const int tid = threadIdx.x;
    const int RO = blockIdx.y * 64;           // 0..512
    const int CO = blockIdx.x * 64;           // 0..32704
    const int b  = CO >> 14;
    const int n0 = CO & 16383;
    const int proj = RO / 192;
    const int wr0  = RO % 192;
    const float* wsel = (proj == 0) ? qw : (proj == 1) ? kw : vw;
    const float* bsel = (proj == 0) ? qb : (proj == 1) ? kb : vb;
    const float* xb = x + (size_t)b * Cc * Nn;

    float acc[4][4] = {};
    const int ty = tid >> 4, tx = tid & 15;

    for (int k0 = 0; k0 < 192; k0 += 32) {
#pragma unroll
        for (int i = 0; i < 2; ++i) {         // W tile: 64 rows x 32 k
            int li = tid + i * 256;
            int row = li >> 3;
            int kq = (li & 7) * 4;
            float4 wv = *(const float4*)(wsel + (size_t)(wr0 + row) * 192 + k0 + kq);
            Wt[kq + 0][row] = wv.x; Wt[kq + 1][row] = wv.y;
            Wt[kq + 2][row] = wv.z; Wt[kq + 3][row] = wv.w;
        }
#pragma unroll
        for (int i = 0; i < 2; ++i) {         // X tile: 32 k x 64 cols
            int li = tid + i * 256;
            int kk = li >> 4;
            int c4 = (li & 15) * 4;
            float4 xv = *(const float4*)(xb + (size_t)(k0 + kk) * Nn + n0 + c4);
            *(float4*)&Xt[kk][c4] = xv;
        }
        __syncthreads();
#pragma unroll
        for (int kk = 0; kk < 32; ++kk) {
            float4 av = *(const float4*)&Wt[kk][ty * 4];
            float4 bv = *(const float4*)&Xt[kk][tx * 4];
            acc[0][0] += av.x * bv.x; acc[0][1] += av.x * bv.y; acc[0][2] += av.x * bv.z; acc[0][3] += av.x * bv.w;
            acc[1][0] += av.y * bv.x; acc[1][1] += av.y * bv.y; acc[1][2] += av.y * bv.z; acc[1][3] += av.y * bv.w;
            acc[2][0] += av.z * bv.x; acc[2][1] += av.z * bv.y; acc[2][2] += av.z * bv.z; acc[2][3] += av.z * bv.w;
            acc[3][0] += av.w * bv.x; acc[3][1] += av.w * bv.y; acc[3][2] += av.w * bv.z; acc[3][3] += av.w * bv.w;
        }
        __syncthreads();
    }

#pragma unroll
    for (int i = 0; i < 4; ++i) {
        int wr = wr0 + ty * 4 + i;
        float bias = bsel[wr];
        int hh = wr >> 5, dd = wr & 31;
#pragma unroll
        for (int j = 0; j < 4; ++j) {
            int n = n0 + tx * 4 + j;
            float v = acc[i][j] + bias;
            if (proj == 0) {
                q_p[((size_t)(b * Cc + wr)) * Nn + n] = v;
            } else {
                float* tdst = (proj == 1) ? k_t : v_t;
                tdst[((size_t)((b * NHc + hh) * Nn + n)) * HDc + dd] = v;
            }
        }
    }
}

// ---------------------------------------------------------------------------
// K2: two depthwise 3x3x3 convs (zero pad) over q: lepe (rpew) and t (odw)
// ---------------------------------------------------------------------------
__global__ __launch_bounds__(256) void dwconv2(
    const float* __restrict__ q_p,
    const float* __restrict__ rpew, const float* __restrict__ rpeb,
    const float* __restrict__ odw,  const float* __restrict__ odb,
    float* __restrict__ lepe, float* __restrict__ t_dw)
{
    int idx = blockIdx.x * 256 + threadIdx.x;     // < 6291456
    int n = idx & 16383;
    int bc = idx >> 14;
    int c = bc % Cc;
    int x = n & 31, y = (n >> 5) & 31, z = n >> 10;
    const float* src = q_p + (size_t)bc * Nn;
    float a1 = 0.f, a2 = 0.f;
#pragma unroll
    for (int kz = 0; kz < 3; ++kz) {
        int zz = z + kz - 1; bool zok = ((unsigned)zz < (unsigned)Dd);
#pragma unroll
        for (int ky = 0; ky < 3; ++ky) {
            int yy = y + ky - 1; bool yok = ((unsigned)yy < (unsigned)Hh);
#pragma unroll
            for (int kx = 0; kx < 3; ++kx) {
                int xx = x + kx - 1; bool xok = ((unsigned)xx < (unsigned)Ww);
                if (zok && yok && xok) {
                    float v = src[(zz * 32 + yy) * 32 + xx];
                    int wi = c * 27 + kz * 9 + ky * 3 + kx;
                    a1 += rpew[wi] * v;
                    a2 += odw[wi] * v;
                }
            }
        }
    }
    lepe[idx] = a1 + rpeb[c];
    t_dw[idx] = a2 + odb[c];
}

// ---------------------------------------------------------------------------
// K3: channel-LN + exact GeLU + 18-row offset projection + tanh
// ---------------------------------------------------------------------------
__global__ __launch_bounds__(256) void ln_offs(
    const float* __restrict__ t_dw,
    const float* __restrict__ lnw, const float* __restrict__ lnb,
    const float* __restrict__ opw, const float* __restrict__ opb,
    float* __restrict__ t3, float* __restrict__ offs_out)
{
    __shared__ float s_stat[2][4][64];
    __shared__ float s_acc[4][18][64];
    const int tid = threadIdx.x;
    const int p = tid >> 6;          // channel part 0..3
    const int l = tid & 63;          // position within block
    const int gb = blockIdx.x;       // 0..511
    const int b = gb >> 8;
    const int n = (gb & 255) * 64 + l;
    const float* src = t_dw + (size_t)b * Cc * Nn + n;

    float s = 0.f, s2 = 0.f;
    for (int c = p * 48; c < p * 48 + 48; ++c) {
        float v = src[(size_t)c * Nn];
        s += v; s2 += v * v;
    }
    s_stat[0][p][l] = s; s_stat[1][p][l] = s2;
    __syncthreads();
    float st  = s_stat[0][0][l] + s_stat[0][1][l] + s_stat[0][2][l] + s_stat[0][3][l];
    float st2 = s_stat[1][0][l] + s_stat[1][1][l] + s_stat[1][2][l] + s_stat[1][3][l];
    float mean = st * (1.f / 192.f);
    float var  = st2 * (1.f / 192.f) - mean * mean;
    float rstd = rsqrtf(var + 1e-5f);

    float acc[18] = {};
    for (int c = p * 48; c < p * 48 + 48; ++c) {
        float v = src[(size_t)c * Nn];
        float xn = (v - mean) * rstd;
        float yv = xn * lnw[c] + lnb[c];
        float g = 0.5f * yv * (1.f + erff(yv * 0.70710678118654752f));
#pragma unroll
        for (int r = 0; r < 18; ++r) acc[r] += opw[r * 192 + c] * g;
    }
#pragma unroll
    for (int r = 0; r < 18; ++r) s_acc[p][r][l] = acc[r];
    __syncthreads();

    if (p < 3) {
#pragma unroll
        for (int hp = 0; hp < 2; ++hp) {
            int hh = p * 2 + hp;
            size_t base = ((size_t)((b * NHc + hh) * Nn) + n) * 3;
#pragma unroll
            for (int i = 0; i < 3; ++i) {
                int r = hh * 3 + i;
                float v = s_acc[0][r][l] + s_acc[1][r][l] + s_acc[2][r][l] + s_acc[3][r][l] + opb[r];
                float t = tanhf(v);
                float sc = (i == 2) ? (2.f / 15.f) : (2.f / 31.f);
                t3[base + i] = t;
                offs_out[base + i] = t * sc;
            }
        }
    }
}

// ---------------------------------------------------------------------------
// K4: deformable attention v5 — v4 structure, register cap removed
// (launch_bounds(256) only; compiler free to allocate ~160-220 VGPR, no spill)
// ---------------------------------------------------------------------------
__device__ __forceinline__ float dot16(const float4* q4, const float* r) {
    const float4* r4 = (const float4*)r;
    float s = 0.f;
#pragma unroll
    for (int i = 0; i < 4; ++i) {
        float4 a = q4[i], b = r4[i];
        s += a.x * b.x + a.y * b.y + a.z * b.z + a.w * b.w;
    }
    return s;
}

__device__ __forceinline__ void axpy16(float4* acc, float w, const float* r) {
    const float4* r4 = (const float4*)r;
#pragma unroll
    for (int i = 0; i < 4; ++i) {
        float4 b = r4[i];
        acc[i].x += w * b.x; acc[i].y += w * b.y;
        acc[i].z += w * b.z; acc[i].w += w * b.w;
    }
}

// load one z-plane of 16 corner dots (static indices only)
#define LOADPL(P, CZO) do {                                                   \
    _Pragma("unroll")                                                         \
    for (int t = 0; t < 16; ++t)                                              \
        P[t] = dot16(qr, kb + (CZO) + cyo[t >> 2] + cxo[t & 3]);              \
} while (0)

// emit 9 scores for sample-plane JZ from corner planes Pg (z=jz) / Pf (z=jz+1)
#define EMITJZ(JZ, Pg, Pf) do {                                               \
    _Pragma("unroll")                                                         \
    for (int jy = 0; jy < 3; ++jy) {                                          \
        _Pragma("unroll")                                                     \
        for (int jx = 0; jx < 3; ++jx) {                                      \
            float cg = yg[jy] * (xg[jx] * Pg[jy*4+jx]     + xf[jx] * Pg[jy*4+jx+1])    \
                     + yf[jy] * (xg[jx] * Pg[(jy+1)*4+jx] + xf[jx] * Pg[(jy+1)*4+jx+1]); \
            float cf = yg[jy] * (xg[jx] * Pf[jy*4+jx]     + xf[jx] * Pf[jy*4+jx+1])    \
                     + yf[jy] * (xg[jx] * Pf[(jy+1)*4+jx] + xf[jx] * Pf[(jy+1)*4+jx+1]); \
            float s = zg[JZ] * cg + zf[JZ] * cf;                              \
            s += __shfl_xor(s, 1);                                            \
            if (hf == 0) {                                                    \
                s_sc[((JZ)*9 + jy*3 + jx) * 128 + qi] = s * SCALEc + brow[(JZ)*9 + jy*3 + jx]; \
            }                                                                 \
        }                                                                     \
    }                                                                         \
} while (0)

// accumulate sample-plane JZ's weights (z-weight WZ) into corner-plane W[16]
#define ADDW(W, JZ, WZ) do {                                                  \
    _Pragma("unroll")                                                         \
    for (int jy = 0; jy < 3; ++jy) {                                          \
        _Pragma("unroll")                                                     \
        for (int jx = 0; jx < 3; ++jx) {                                      \
            float aj = expf(s_sc[((JZ)*9+jy*3+jx)*128+qi] - m) * inv * (WZ);  \
            W[jy*4+jx]         += aj * yg[jy] * xg[jx];                       \
            W[jy*4+jx+1]       += aj * yg[jy] * xf[jx];                       \
            W[(jy+1)*4+jx]     += aj * yf[jy] * xg[jx];                       \
            W[(jy+1)*4+jx+1]   += aj * yf[jy] * xf[jx];                       \
        }                                                                     \
    }                                                                         \
} while (0)

#define AXPYPL(W, CZO) do {                                                   \
    _Pragma("unroll")                                                         \
    for (int t = 0; t < 16; ++t)                                              \
        axpy16(acc, W[t], vb + (CZO) + cyo[t >> 2] + cxo[t & 3]);             \
} while (0)

__global__ __launch_bounds__(256) void attn_kernel(
    const float* __restrict__ q_p, const float* __restrict__ k_t,
    const float* __restrict__ v_t, const float* __restrict__ t3,
    const float* __restrict__ bias0, const float* __restrict__ bias1,
    float* __restrict__ ol, float* __restrict__ pe)
{
    __shared__ float s_sc[27 * 128];   // raw scores, one slot per query
    __shared__ float s_red[4];
    const int tid = threadIdx.x;
    // XCD-aware bijective swizzle: 1536 = 8 * 192
    const int wid = (blockIdx.x & 7) * 192 + (blockIdx.x >> 3);
    const int bh = wid >> 7;           // 128 blocks per bh
    const int nt = wid & 127;
    const int qi = tid >> 1;           // query within block 0..127
    const int hf = tid & 1;            // head-dim half
    const int n = nt * 128 + qi;
    const int b = bh / NHc, h = bh % NHc;
    const int dil = (h < 3) ? 1 : 2;
    const float* brow = (h < 3) ? (bias0 + h * 27) : (bias1 + (h - 3) * 27);
    const int x = n & 31, y = (n >> 5) & 31, z = n >> 10;

    const float* t3p = t3 + ((size_t)bh * Nn + n) * 3;
    const float pxb = (float)x + t3p[0];
    const float pyb = (float)y + t3p[1];
    const float pzb = (float)z + t3p[2];

    // per-axis per-sample clamp/floor precompute (all three axes)
    int xi0[3], xi1[3]; float xf[3], xg[3];
    int yi0[3], yi1[3]; float yf[3], yg[3];
    int zi0[3], zi1[3]; float zf[3], zg[3];
#pragma unroll
    for (int jj = 0; jj < 3; ++jj) {
        float p = fminf(fmaxf(pxb + (float)((jj - 1) * dil), 0.f), 31.f);
        float f0 = floorf(p); int i0 = (int)f0;
        xi0[jj] = i0 * HDc; xi1[jj] = min(i0 + 1, 31) * HDc;
        xf[jj] = p - f0; xg[jj] = 1.f - xf[jj];
        p = fminf(fmaxf(pyb + (float)((jj - 1) * dil), 0.f), 31.f);
        f0 = floorf(p); i0 = (int)f0;
        yi0[jj] = i0 * (Ww * HDc); yi1[jj] = min(i0 + 1, 31) * (Ww * HDc);
        yf[jj] = p - f0; yg[jj] = 1.f - yf[jj];
        p = fminf(fmaxf(pzb + (float)((jj - 1) * dil), 0.f), 15.f);
        f0 = floorf(p); i0 = (int)f0;
        zi0[jj] = i0 * (Hh * Ww * HDc); zi1[jj] = min(i0 + 1, 15) * (Hh * Ww * HDc);
        zf[jj] = p - f0; zg[jj] = 1.f - zf[jj];
    }

    // q half (16 dims) from planar layout: coalesced strided loads
    float4 qr[4];
    {
        const float* qsrc = q_p + ((size_t)(b * Cc + h * HDc + hf * 16)) * Nn + n;
#pragma unroll
        for (int i = 0; i < 4; ++i) {
            qr[i].x = qsrc[(size_t)(4 * i + 0) * Nn];
            qr[i].y = qsrc[(size_t)(4 * i + 1) * Nn];
            qr[i].z = qsrc[(size_t)(4 * i + 2) * Nn];
            qr[i].w = qsrc[(size_t)(4 * i + 3) * Nn];
        }
    }
    const float* kb = k_t + (size_t)bh * Nn * HDc + hf * 16;
    const float* vb = v_t + (size_t)bh * Nn * HDc + hf * 16;

    if (h < 3) {
        // ---------------- dil=1: 4x4x4 corner-dedup path ----------------
        // corner lists; exact under clamping (mismatched corners have w=0)
        const int cxo[4] = { xi0[0], xi0[1], xi0[2], xi1[2] };
        const int cyo[4] = { yi0[0], yi0[1], yi0[2], yi1[2] };
        const int czo0 = zi0[0], czo1 = zi0[1], czo2 = zi0[2], czo3 = zi1[2];

        // pass 1: straight-line rolling planes (named arrays, no aliasing)
        float plA[16], plB[16];
        LOADPL(plA, czo0);             // corner plane 0
        LOADPL(plB, czo1);             // corner plane 1
        EMITJZ(0, plA, plB);
        LOADPL(plA, czo2);             // corner plane 2 (overwrites 0)
        EMITJZ(1, plB, plA);
        LOADPL(plB, czo3);             // corner plane 3 (overwrites 1)
        EMITJZ(2, plA, plB);
        __syncthreads();

        // softmax stats over 27
        float m = -1e30f;
#pragma unroll
        for (int j = 0; j < 27; ++j) m = fmaxf(m, s_sc[j * 128 + qi]);
        float ssum = 0.f;
#pragma unroll
        for (int j = 0; j < 27; ++j) ssum += expf(s_sc[j * 128 + qi] - m);
        const float inv = 1.f / ssum;

        // pass 2: per-corner-plane weights, straight-line
        float4 acc[4] = {};
        {
            float W[16] = {};
            ADDW(W, 0, zg[0]);
            AXPYPL(W, czo0);
        }
        {
            float W[16] = {};
            ADDW(W, 0, zf[0]);
            ADDW(W, 1, zg[1]);
            AXPYPL(W, czo1);
        }
        {
            float W[16] = {};
            ADDW(W, 1, zf[1]);
            ADDW(W, 2, zg[2]);
            AXPYPL(W, czo2);
        }
        {
            float W[16] = {};
            ADDW(W, 2, zf[2]);
            AXPYPL(W, czo3);
        }

        // epilogue: write o + lepe, |o| partial
        float* dst = ol + ((size_t)(b * Cc + h * HDc + hf * 16)) * Nn + n;
        float sabs = 0.f;
#pragma unroll
        for (int i = 0; i < 4; ++i) {
            float o0 = acc[i].x, o1 = acc[i].y, o2 = acc[i].z, o3 = acc[i].w;
            sabs += fabsf(o0) + fabsf(o1) + fabsf(o2) + fabsf(o3);
            size_t i0 = (size_t)(4 * i + 0) * Nn, i1 = (size_t)(4 * i + 1) * Nn;
            size_t i2 = (size_t)(4 * i + 2) * Nn, i3 = (size_t)(4 * i + 3) * Nn;
            dst[i0] = o0 + dst[i0];
            dst[i1] = o1 + dst[i1];
            dst[i2] = o2 + dst[i2];
            dst[i3] = o3 + dst[i3];
        }
#pragma unroll
        for (int o = 32; o > 0; o >>= 1) sabs += __shfl_down(sabs, o, 64);
        if ((tid & 63) == 0) s_red[tid >> 6] = sabs;
        __syncthreads();
        if (tid == 0) pe[wid] = s_red[0] + s_red[1] + s_red[2] + s_red[3];
        return;
    }

    // ---------------- dil=2: generic 27x8 path (no structural dedup) ----
    for (int jz = 0; jz < 3; ++jz) {
        int z0 = zi0[jz], z1 = zi1[jz];
        float zfv = zf[jz], zgv = zg[jz];
#pragma unroll
        for (int jy = 0; jy < 3; ++jy) {
#pragma unroll
            for (int jx = 0; jx < 3; ++jx) {
                float d00 = xg[jx] * dot16(qr, kb + z0 + yi0[jy] + xi0[jx])
                          + xf[jx] * dot16(qr, kb + z0 + yi0[jy] + xi1[jx]);
                float d01 = xg[jx] * dot16(qr, kb + z0 + yi1[jy] + xi0[jx])
                          + xf[jx] * dot16(qr, kb + z0 + yi1[jy] + xi1[jx]);
                float d10 = xg[jx] * dot16(qr, kb + z1 + yi0[jy] + xi0[jx])
                          + xf[jx] * dot16(qr, kb + z1 + yi0[jy] + xi1[jx]);
                float d11 = xg[jx] * dot16(qr, kb + z1 + yi1[jy] + xi0[jx])
                          + xf[jx] * dot16(qr, kb + z1 + yi1[jy] + xi1[jx]);
                float s = zgv * (yg[jy] * d00 + yf[jy] * d01)
                        + zfv * (yg[jy] * d10 + yf[jy] * d11);
                s += __shfl_xor(s, 1);
                if (hf == 0) {
                    int j = jz * 9 + jy * 3 + jx;
                    s_sc[j * 128 + qi] = s * SCALEc + brow[j];
                }
            }
        }
    }
    __syncthreads();

    float m = -1e30f;
#pragma unroll
    for (int j = 0; j < 27; ++j) m = fmaxf(m, s_sc[j * 128 + qi]);
    float ssum = 0.f;
#pragma unroll
    for (int j = 0; j < 27; ++j) ssum += expf(s_sc[j * 128 + qi] - m);
    const float inv = 1.f / ssum;

    float4 acc[4] = {};
    for (int jz = 0; jz < 3; ++jz) {
        int z0 = zi0[jz], z1 = zi1[jz];
        float zfv = zf[jz], zgv = zg[jz];
#pragma unroll
        for (int jy = 0; jy < 3; ++jy) {
#pragma unroll
            for (int jx = 0; jx < 3; ++jx) {
                int j = jz * 9 + jy * 3 + jx;
                float aj = expf(s_sc[j * 128 + qi] - m) * inv;
                float wz0 = aj * zgv, wz1 = aj * zfv;
                float w00 = wz0 * yg[jy], w01 = wz0 * yf[jy];
                float w10 = wz1 * yg[jy], w11 = wz1 * yf[jy];
                axpy16(acc, w00 * xg[jx], vb + z0 + yi0[jy] + xi0[jx]);
                axpy16(acc, w00 * xf[jx], vb + z0 + yi0[jy] + xi1[jx]);
                axpy16(acc, w01 * xg[jx], vb + z0 + yi1[jy] + xi0[jx]);
                axpy16(acc, w01 * xf[jx], vb + z0 + yi1[jy] + xi1[jx]);
                axpy16(acc, w10 * xg[jx], vb + z1 + yi0[jy] + xi0[jx]);
                axpy16(acc, w10 * xf[jx], vb + z1 + yi0[jy] + xi1[jx]);
                axpy16(acc, w11 * xg[jx], vb + z1 + yi1[jy] + xi0[jx]);
                axpy16(acc, w11 * xf[jx], vb + z1 + yi1[jy] + xi1[jx]);
            }
        }
    }

    float* dst = ol + ((size_t)(b * Cc + h * HDc + hf * 16)) * Nn + n;
    float sabs = 0.f;
#pragma unroll
    for (int i = 0; i < 4; ++i) {
        float o0 = acc[i].x, o1 = acc[i].y, o2 = acc[i].z, o3 = acc[i].w;
        sabs += fabsf(o0) + fabsf(o1) + fabsf(o2) + fabsf(o3);
        size_t i0 = (size_t)(4 * i + 0) * Nn, i1 = (size_t)(4 * i + 1) * Nn;
        size_t i2 = (size_t)(4 * i + 2) * Nn, i3 = (size_t)(4 * i + 3) * Nn;
        dst[i0] = o0 + dst[i0];
        dst[i1] = o1 + dst[i1];
        dst[i2] = o2 + dst[i2];
        dst[i3] = o3 + dst[i3];
    }
#pragma unroll
    for (int o = 32; o > 0; o >>= 1) sabs += __shfl_down(sabs, o, 64);
    if ((tid & 63) == 0) s_red[tid >> 6] = sabs;
    __syncthreads();
    if (tid == 0) pe[wid] = s_red[0] + s_red[1] + s_red[2] + s_red[3];
}

// ---------------------------------------------------------------------------
// K5: final projection GEMM  out = pw @ ol + pb    (ol = o + lepe)
// ---------------------------------------------------------------------------
__global__ __launch_bounds__(256) void gemm_out(
    const float* __restrict__ ol,
    const float* __restrict__ pw, const float* __restrict__ pb,
    float* __restrict__ out)
{
    __shared__ float Wt[32][68];
    __shared__ float Xt[32][68];
    const int tid = threadIdx.x;
    const int RO = blockIdx.y * 64;           // 0..128
    const int CO = blockIdx.x * 64;
    const int b  = CO >> 14;
    const int n0 = CO & 16383;
    const size_t xoff = (size_t)b * Cc * Nn + n0;

    float acc[4][4] = {};
    const int ty = tid >> 4, tx = tid & 15;

    for (int k0 = 0; k0 < 192; k0 += 32) {
#pragma unroll
        for (int i = 0; i < 2; ++i) {
            int li = tid + i * 256;
            int row = li >> 3;
            int kq = (li & 7) * 4;
            float4 wv = *(const float4*)(pw + (size_t)(RO + row) * 192 + k0 + kq);
            Wt[kq + 0][row] = wv.x; Wt[kq + 1][row] = wv.y;
            Wt[kq + 2][row] = wv.z; Wt[kq + 3][row] = wv.w;
        }
#pragma unroll
        for (int i = 0; i < 2; ++i) {
            int li = tid + i * 256;
            int kk = li >> 4;
            int c4 = (li & 15) * 4;
            float4 xv = *(const float4*)(ol + xoff + (size_t)(k0 + kk) * Nn + c4);
            *(float4*)&Xt[kk][c4] = xv;
        }
        __syncthreads();
#pragma unroll
        for (int kk = 0; kk < 32; ++kk) {
            float4 av = *(const float4*)&Wt[kk][ty * 4];
            float4 bv = *(const float4*)&Xt[kk][tx * 4];
            acc[0][0] += av.x * bv.x; acc[0][1] += av.x * bv.y; acc[0][2] += av.x * bv.z; acc[0][3] += av.x * bv.w;
            acc[1][0] += av.y * bv.x; acc[1][1] += av.y * bv.y; acc[1][2] += av.y * bv.z; acc[1][3] += av.y * bv.w;
            acc[2][0] += av.z * bv.x; acc[2][1] += av.z * bv.y; acc[2][2] += av.z * bv.z; acc[2][3] += av.z * bv.w;
            acc[3][0] += av.w * bv.x; acc[3][1] += av.w * bv.y; acc[3][2] += av.w * bv.z; acc[3][3] += av.w * bv.w;
        }
        __syncthreads();
    }
#pragma unroll
    for (int i = 0; i < 4; ++i) {
        int r = RO + ty * 4 + i;
        float bias = pb[r];
#pragma unroll
        for (int j = 0; j < 4; ++j) {
            out[((size_t)(b * Cc + r)) * Nn + n0 + tx * 4 + j] = acc[i][j] + bias;
        }
    }
}

// ---------------------------------------------------------------------------
// Reductions
// ---------------------------------------------------------------------------
__global__ __launch_bounds__(256) void mag_stage1(const float* __restrict__ offs, float* __restrict__ pm) {
    __shared__ float sm[4];
    int g = blockIdx.x >> 3, chunk = blockIdx.x & 7;   // g = bh (0..11)
    int tid = threadIdx.x;
    float s = 0.f;
    for (int i = tid; i < 2048; i += 256) {
        size_t base = ((size_t)g * Nn + chunk * 2048 + i) * 3;
        float a = offs[base], b = offs[base + 1], c = offs[base + 2];
        s += sqrtf(a * a + b * b + c * c);
    }
#pragma unroll
    for (int o = 32; o > 0; o >>= 1) s += __shfl_down(s, o, 64);
    if ((tid & 63) == 0) sm[tid >> 6] = s;
    __syncthreads();
    if (tid == 0) pm[blockIdx.x] = sm[0] + sm[1] + sm[2] + sm[3];
}

__global__ __launch_bounds__(64) void finalize_k(const float* __restrict__ pm, const float* __restrict__ pe,
                                                 float* __restrict__ out) {
    int tid = threadIdx.x;
    if (tid < 12) {
        float s = 0.f;
#pragma unroll
        for (int i = 0; i < 8; ++i) s += pm[tid * 8 + i];
        float mag = s / 16384.f;
        out[OUT_MAG + tid] = mag;
        int b = tid / 6, h = tid % 6;
        out[OUT_GUIDE + b * 8 + h] = mag;
    }
    if (tid < 4) {
        int b = tid >> 1, br = tid & 1;
        float s = 0.f;
        for (int hh = 0; hh < 3; ++hh)
            for (int c = 0; c < 128; ++c)
                s += pe[((b * NHc) + br * 3 + hh) * 128 + c];
        float e = s / 1572864.f;     // 3 heads * 32 dims * 16384 positions
        out[OUT_EN + tid] = e;
        out[OUT_GUIDE + b * 8 + 6 + br] = e;
    }
}

// ---------------------------------------------------------------------------
extern "C" void kernel_launch(void* const* d_in, const int* in_sizes, int n_in,
                              void* d_out, int out_size, void* d_ws, size_t ws_size,
                              hipStream_t stream) {
    const float* x    = (const float*)d_in[0];
    const float* qw   = (const float*)d_in[1];
    const float* qb   = (const float*)d_in[2];
    const float* kw   = (const float*)d_in[3];
    const float* kb   = (const float*)d_in[4];
    const float* vw   = (const float*)d_in[5];
    const float* vb   = (const float*)d_in[6];
    const float* pw   = (const float*)d_in[7];
    const float* pb   = (const float*)d_in[8];
    const float* odw  = (const float*)d_in[9];
    const float* odb  = (const float*)d_in[10];
    const float* lnw  = (const float*)d_in[11];
    const float* lnb  = (const float*)d_in[12];
    const float* opw  = (const float*)d_in[13];
    const float* opb  = (const float*)d_in[14];
    const float* rpew = (const float*)d_in[15];
    const float* rpeb = (const float*)d_in[16];
    const float* bias0 = (const float*)d_in[17];
    const float* bias1 = (const float*)d_in[18];

    float* ws = (float*)d_ws;
    float* q_p  = ws;                            // BIG
    float* k_t  = ws + (size_t)BIG;              // BIG
    float* v_t  = ws + (size_t)2 * BIG;          // BIG
    float* ol   = ws + (size_t)3 * BIG;          // BIG (lepe, then o+lepe)
    float* t_dw = ws + (size_t)4 * BIG;          // BIG
    float* t3   = ws + (size_t)5 * BIG;          // 589824
    float* pm   = t3 + 589824;                   // 96
    float* pe   = pm + 96;                       // 1536

    float* out = (float*)d_out;
    float* offs_out = out + OUT_OFFS;

    gemm_qkv<<<dim3(512, 9), 256, 0, stream>>>(x, qw, qb, kw, kb, vw, vb, q_p, k_t, v_t);
    dwconv2<<<24576, 256, 0, stream>>>(q_p, rpew, rpeb, odw, odb, ol, t_dw);
    ln_offs<<<512, 256, 0, stream>>>(t_dw, lnw, lnb, opw, opb, t3, offs_out);
    attn_kernel<<<1536, 256, 0, stream>>>(q_p, k_t, v_t, t3, bias0, bias1, ol, pe);
    gemm_out<<<dim3(512, 3), 256, 0, stream>>>(ol, pw, pb, out);
    mag_stage1<<<96, 256, 0, stream>>>(offs_out, pm);
    finalize_k<<<1, 64, 0, stream>>>(pm, pe, out);
}

// Round 10
// 702.398 us; speedup vs baseline: 1.5732x; 1.3513x over previous
//
#include <hip/hip_runtime.h>
#include <hip/hip_bf16.h>
#include <hip/hip_fp16.h>

// Problem constants
#define Bc   2
#define Cc   192
#define NHc  6
#define HDc  32
#define Dd   16
#define Hh   32
#define Ww   32
#define Nn   16384          // Dd*Hh*Ww
#define SCALEc 0.17677669529663687f   // 32^-0.5

// d_out layout (floats):
//   out        [B,192,N]      @ 0          (6291456)
//   offs       [B,6,N,3]      @ 6291456    (589824)
//   offset_mag [B,6]          @ 6881280    (12)
//   branch_en  [B,2]          @ 6881292    (4)
//   guide      [B,8]          @ 6881296    (16)
#define OUT_OFFS   6291456
#define OUT_MAG    6881280
#define OUT_EN     6881292
#define OUT_GUIDE  6881296

#define BIG 6291456   // B*C*N floats
// ws layout (floats): q_p @0, q_t @BIG, kh @2BIG (BIG halfs), vh @2BIG+BIG/2,
//                     ol @3BIG, t_dw @4BIG, t3 @5BIG (589824), pm(96), pe(3072)

// ---------------------------------------------------------------------------
// K1: fused QKV projection GEMM.  rows 0..575 = [qw;kw;vw] @ x  (+bias)
// q -> planar [b,c,n] AND transposed fp32 [bh,n,32]; k,v -> fp16 [bh,n,32]
// ---------------------------------------------------------------------------
__global__ __launch_bounds__(256) void gemm_qkv(
    const float* __restrict__ x,
    const float* __restrict__ qw, const float* __restrict__ qb,
    const float* __restrict__ kw, const float* __restrict__ kb,
    const float* __restrict__ vw, const float* __restrict__ vb,
    float* __restrict__ q_p, float* __restrict__ q_t,
    __half* __restrict__ kh, __half* __restrict__ vh)
{
    __shared__ float Wt[32][68];   // [kk][row]
    __shared__ float Xt[32][68];   // [kk][col]
    const int tid = threadIdx.x;
    const int RO = blockIdx.y * 64;           // 0..512
    const int CO = blockIdx.x * 64;           // 0..32704
    const int b  = CO >> 14;
    const int n0 = CO & 16383;
    const int proj = RO / 192;
    const int wr0  = RO % 192;
    const float* wsel = (proj == 0) ? qw : (proj == 1) ? kw : vw;
    const float* bsel = (proj == 0) ? qb : (proj == 1) ? kb : vb;
    const float* xb = x + (size_t)b * Cc * Nn;

    float acc[4][4] = {};
    const int ty = tid >> 4, tx = tid & 15;

    for (int k0 = 0; k0 < 192; k0 += 32) {
#pragma unroll
        for (int i = 0; i < 2; ++i) {         // W tile: 64 rows x 32 k
            int li = tid + i * 256;
            int row = li >> 3;
            int kq = (li & 7) * 4;
            float4 wv = *(const float4*)(wsel + (size_t)(wr0 + row) * 192 + k0 + kq);
            Wt[kq + 0][row] = wv.x; Wt[kq + 1][row] = wv.y;
            Wt[kq + 2][row] = wv.z; Wt[kq + 3][row] = wv.w;
        }
#pragma unroll
        for (int i = 0; i < 2; ++i) {         // X tile: 32 k x 64 cols
            int li = tid + i * 256;
            int kk = li >> 4;
            int c4 = (li & 15) * 4;
            float4 xv = *(const float4*)(xb + (size_t)(k0 + kk) * Nn + n0 + c4);
            *(float4*)&Xt[kk][c4] = xv;
        }
        __syncthreads();
#pragma unroll
        for (int kk = 0; kk < 32; ++kk) {
            float4 av = *(const float4*)&Wt[kk][ty * 4];
            float4 bv = *(const float4*)&Xt[kk][tx * 4];
            acc[0][0] += av.x * bv.x; acc[0][1] += av.x * bv.y; acc[0][2] += av.x * bv.z; acc[0][3] += av.x * bv.w;
            acc[1][0] += av.y * bv.x; acc[1][1] += av.y * bv.y; acc[1][2] += av.y * bv.z; acc[1][3] += av.y * bv.w;
            acc[2][0] += av.z * bv.x; acc[2][1] += av.z * bv.y; acc[2][2] += av.z * bv.z; acc[2][3] += av.z * bv.w;
            acc[3][0] += av.w * bv.x; acc[3][1] += av.w * bv.y; acc[3][2] += av.w * bv.z; acc[3][3] += av.w * bv.w;
        }
        __syncthreads();
    }

#pragma unroll
    for (int i = 0; i < 4; ++i) {
        int wr = wr0 + ty * 4 + i;
        float bias = bsel[wr];
        int hh = wr >> 5, dd = wr & 31;
#pragma unroll
        for (int j = 0; j < 4; ++j) {
            int n = n0 + tx * 4 + j;
            float v = acc[i][j] + bias;
            size_t toff = ((size_t)((b * NHc + hh) * Nn + n)) * HDc + dd;
            if (proj == 0) {
                q_p[((size_t)(b * Cc + wr)) * Nn + n] = v;
                q_t[toff] = v;
            } else if (proj == 1) {
                kh[toff] = __float2half(v);
            } else {
                vh[toff] = __float2half(v);
            }
        }
    }
}

// ---------------------------------------------------------------------------
// K2: two depthwise 3x3x3 convs (zero pad) over q: lepe (rpew) and t (odw)
// ---------------------------------------------------------------------------
__global__ __launch_bounds__(256) void dwconv2(
    const float* __restrict__ q_p,
    const float* __restrict__ rpew, const float* __restrict__ rpeb,
    const float* __restrict__ odw,  const float* __restrict__ odb,
    float* __restrict__ lepe, float* __restrict__ t_dw)
{
    int idx = blockIdx.x * 256 + threadIdx.x;     // < 6291456
    int n = idx & 16383;
    int bc = idx >> 14;
    int c = bc % Cc;
    int x = n & 31, y = (n >> 5) & 31, z = n >> 10;
    const float* src = q_p + (size_t)bc * Nn;
    float a1 = 0.f, a2 = 0.f;
#pragma unroll
    for (int kz = 0; kz < 3; ++kz) {
        int zz = z + kz - 1; bool zok = ((unsigned)zz < (unsigned)Dd);
#pragma unroll
        for (int ky = 0; ky < 3; ++ky) {
            int yy = y + ky - 1; bool yok = ((unsigned)yy < (unsigned)Hh);
#pragma unroll
            for (int kx = 0; kx < 3; ++kx) {
                int xx = x + kx - 1; bool xok = ((unsigned)xx < (unsigned)Ww);
                if (zok && yok && xok) {
                    float v = src[(zz * 32 + yy) * 32 + xx];
                    int wi = c * 27 + kz * 9 + ky * 3 + kx;
                    a1 += rpew[wi] * v;
                    a2 += odw[wi] * v;
                }
            }
        }
    }
    lepe[idx] = a1 + rpeb[c];
    t_dw[idx] = a2 + odb[c];
}

// ---------------------------------------------------------------------------
// K3: channel-LN + exact GeLU + 18-row offset projection + tanh
// ---------------------------------------------------------------------------
__global__ __launch_bounds__(256) void ln_offs(
    const float* __restrict__ t_dw,
    const float* __restrict__ lnw, const float* __restrict__ lnb,
    const float* __restrict__ opw, const float* __restrict__ opb,
    float* __restrict__ t3, float* __restrict__ offs_out)
{
    __shared__ float s_stat[2][4][64];
    __shared__ float s_acc[4][18][64];
    const int tid = threadIdx.x;
    const int p = tid >> 6;          // channel part 0..3
    const int l = tid & 63;          // position within block
    const int gb = blockIdx.x;       // 0..511
    const int b = gb >> 8;
    const int n = (gb & 255) * 64 + l;
    const float* src = t_dw + (size_t)b * Cc * Nn + n;

    float s = 0.f, s2 = 0.f;
    for (int c = p * 48; c < p * 48 + 48; ++c) {
        float v = src[(size_t)c * Nn];
        s += v; s2 += v * v;
    }
    s_stat[0][p][l] = s; s_stat[1][p][l] = s2;
    __syncthreads();
    float st  = s_stat[0][0][l] + s_stat[0][1][l] + s_stat[0][2][l] + s_stat[0][3][l];
    float st2 = s_stat[1][0][l] + s_stat[1][1][l] + s_stat[1][2][l] + s_stat[1][3][l];
    float mean = st * (1.f / 192.f);
    float var  = st2 * (1.f / 192.f) - mean * mean;
    float rstd = rsqrtf(var + 1e-5f);

    float acc[18] = {};
    for (int c = p * 48; c < p * 48 + 48; ++c) {
        float v = src[(size_t)c * Nn];
        float xn = (v - mean) * rstd;
        float yv = xn * lnw[c] + lnb[c];
        float g = 0.5f * yv * (1.f + erff(yv * 0.70710678118654752f));
#pragma unroll
        for (int r = 0; r < 18; ++r) acc[r] += opw[r * 192 + c] * g;
    }
#pragma unroll
    for (int r = 0; r < 18; ++r) s_acc[p][r][l] = acc[r];
    __syncthreads();

    if (p < 3) {
#pragma unroll
        for (int hp = 0; hp < 2; ++hp) {
            int hh = p * 2 + hp;
            size_t base = ((size_t)((b * NHc + hh) * Nn) + n) * 3;
#pragma unroll
            for (int i = 0; i < 3; ++i) {
                int r = hh * 3 + i;
                float v = s_acc[0][r][l] + s_acc[1][r][l] + s_acc[2][r][l] + s_acc[3][r][l] + opb[r];
                float t = tanhf(v);
                float sc = (i == 2) ? (2.f / 15.f) : (2.f / 31.f);
                t3[base + i] = t;
                offs_out[base + i] = t * sc;
            }
        }
    }
}

// ---------------------------------------------------------------------------
// K4: deformable attention v6 — 4 threads/query (8 dims each), fp16 K/V,
// streaming sc[27] register accumulation (one corner plane live at a time).
// ---------------------------------------------------------------------------
__device__ __forceinline__ float dot8h(const float* q8, const __half* r) {
    union { float4 f; __half2 h2[4]; } u;
    u.f = *(const float4*)r;            // 8 halfs, 16B aligned
    float s = 0.f;
#pragma unroll
    for (int i = 0; i < 4; ++i) {
        float2 f = __half22float2(u.h2[i]);
        s += q8[2 * i] * f.x + q8[2 * i + 1] * f.y;
    }
    return s;
}

__device__ __forceinline__ void axpy8h(float* acc8, float w, const __half* r) {
    union { float4 f; __half2 h2[4]; } u;
    u.f = *(const float4*)r;
#pragma unroll
    for (int i = 0; i < 4; ++i) {
        float2 f = __half22float2(u.h2[i]);
        acc8[2 * i]     += w * f.x;
        acc8[2 * i + 1] += w * f.y;
    }
}

// load one z-plane of 16 corner dots (static indices only)
#define LOADP(CZO) do {                                                       \
    _Pragma("unroll")                                                         \
    for (int t = 0; t < 16; ++t)                                              \
        pl[t] = dot8h(q8, kb + (CZO) + cyo[t >> 2] + cxo[t & 3]);             \
} while (0)

// accumulate plane TZ's contribution into sc[27] (TZ is a literal)
#define ACCP(TZ) do {                                                         \
    _Pragma("unroll")                                                         \
    for (int jy = 0; jy < 3; ++jy) {                                          \
        _Pragma("unroll")                                                     \
        for (int jx = 0; jx < 3; ++jx) {                                      \
            float bil = yg[jy] * (xg[jx] * pl[jy*4+jx]     + xf[jx] * pl[jy*4+jx+1])   \
                      + yf[jy] * (xg[jx] * pl[(jy+1)*4+jx] + xf[jx] * pl[(jy+1)*4+jx+1]); \
            if ((TZ) <= 2) sc[(TZ)*9 + jy*3 + jx]     += zg[TZ] * bil;        \
            if ((TZ) >= 1) sc[((TZ)-1)*9 + jy*3 + jx] += zf[(TZ)-1] * bil;    \
        }                                                                     \
    }                                                                         \
} while (0)

// accumulate sample-plane JZ's weights (z-weight WZ) into corner-plane W[16]
#define ADDW(W, JZ, WZ) do {                                                  \
    _Pragma("unroll")                                                         \
    for (int jy = 0; jy < 3; ++jy) {                                          \
        _Pragma("unroll")                                                     \
        for (int jx = 0; jx < 3; ++jx) {                                      \
            float aj = expf(s_sc[((JZ)*9+jy*3+jx)*64+qi] - m) * inv * (WZ);   \
            W[jy*4+jx]         += aj * yg[jy] * xg[jx];                       \
            W[jy*4+jx+1]       += aj * yg[jy] * xf[jx];                       \
            W[(jy+1)*4+jx]     += aj * yf[jy] * xg[jx];                       \
            W[(jy+1)*4+jx+1]   += aj * yf[jy] * xf[jx];                       \
        }                                                                     \
    }                                                                         \
} while (0)

#define AXPYPL(W, CZO) do {                                                   \
    _Pragma("unroll")                                                         \
    for (int t = 0; t < 16; ++t)                                              \
        axpy8h(acc8, W[t], vb + (CZO) + cyo[t >> 2] + cxo[t & 3]);            \
} while (0)

__global__ __launch_bounds__(256) void attn_kernel(
    const float* __restrict__ q_t, const __half* __restrict__ kh,
    const __half* __restrict__ vh, const float* __restrict__ t3,
    const float* __restrict__ bias0, const float* __restrict__ bias1,
    float* __restrict__ ol, float* __restrict__ pe)
{
    __shared__ float s_sc[27 * 64];    // raw scores, one slot per query
    __shared__ float s_red[4];
    const int tid = threadIdx.x;
    // XCD-aware bijective swizzle: 3072 = 8 * 384
    const int wid = (blockIdx.x & 7) * 384 + (blockIdx.x >> 3);
    const int bh = wid >> 8;           // 256 blocks per bh
    const int nt = wid & 255;
    const int qi = tid >> 2;           // query within block 0..63
    const int hf = tid & 3;            // head-dim quarter (8 dims)
    const int n = nt * 64 + qi;
    const int b = bh / NHc, h = bh % NHc;
    const int dil = (h < 3) ? 1 : 2;
    const float* brow = (h < 3) ? (bias0 + h * 27) : (bias1 + (h - 3) * 27);
    const int x = n & 31, y = (n >> 5) & 31, z = n >> 10;

    const float* t3p = t3 + ((size_t)bh * Nn + n) * 3;
    const float pxb = (float)x + t3p[0];
    const float pyb = (float)y + t3p[1];
    const float pzb = (float)z + t3p[2];

    // per-axis per-sample clamp/floor precompute (all three axes)
    int xi0[3], xi1[3]; float xf[3], xg[3];
    int yi0[3], yi1[3]; float yf[3], yg[3];
    int zi0[3], zi1[3]; float zf[3], zg[3];
#pragma unroll
    for (int jj = 0; jj < 3; ++jj) {
        float p = fminf(fmaxf(pxb + (float)((jj - 1) * dil), 0.f), 31.f);
        float f0 = floorf(p); int i0 = (int)f0;
        xi0[jj] = i0 * HDc; xi1[jj] = min(i0 + 1, 31) * HDc;
        xf[jj] = p - f0; xg[jj] = 1.f - xf[jj];
        p = fminf(fmaxf(pyb + (float)((jj - 1) * dil), 0.f), 31.f);
        f0 = floorf(p); i0 = (int)f0;
        yi0[jj] = i0 * (Ww * HDc); yi1[jj] = min(i0 + 1, 31) * (Ww * HDc);
        yf[jj] = p - f0; yg[jj] = 1.f - yf[jj];
        p = fminf(fmaxf(pzb + (float)((jj - 1) * dil), 0.f), 15.f);
        f0 = floorf(p); i0 = (int)f0;
        zi0[jj] = i0 * (Hh * Ww * HDc); zi1[jj] = min(i0 + 1, 15) * (Hh * Ww * HDc);
        zf[jj] = p - f0; zg[jj] = 1.f - zf[jj];
    }

    // q slice (8 dims, fp32) from transposed q_t: fully coalesced
    float q8[8];
    {
        const float* qsrc = q_t + ((size_t)bh * Nn + n) * HDc + hf * 8;
        float4 qa = *(const float4*)qsrc;
        float4 qb2 = *(const float4*)(qsrc + 4);
        q8[0] = qa.x; q8[1] = qa.y; q8[2] = qa.z; q8[3] = qa.w;
        q8[4] = qb2.x; q8[5] = qb2.y; q8[6] = qb2.z; q8[7] = qb2.w;
    }
    const __half* kb = kh + (size_t)bh * Nn * HDc + hf * 8;
    const __half* vb = vh + (size_t)bh * Nn * HDc + hf * 8;

    if (h < 3) {
        // ---------------- dil=1: 4x4x4 corner-dedup path ----------------
        const int cxo[4] = { xi0[0], xi0[1], xi0[2], xi1[2] };
        const int cyo[4] = { yi0[0], yi0[1], yi0[2], yi1[2] };
        const int czo0 = zi0[0], czo1 = zi0[1], czo2 = zi0[2], czo3 = zi1[2];

        // pass 1: stream 4 corner planes, accumulate into sc[27]
        float sc[27];
#pragma unroll
        for (int j = 0; j < 27; ++j) sc[j] = 0.f;
        float pl[16];
        LOADP(czo0); ACCP(0);
        LOADP(czo1); ACCP(1);
        LOADP(czo2); ACCP(2);
        LOADP(czo3); ACCP(3);

#pragma unroll
        for (int j = 0; j < 27; ++j) {
            float s = sc[j];
            s += __shfl_xor(s, 1);
            s += __shfl_xor(s, 2);
            if (hf == 0) s_sc[j * 64 + qi] = s * SCALEc + brow[j];
        }
        __syncthreads();

        // softmax stats over 27
        float m = -1e30f;
#pragma unroll
        for (int j = 0; j < 27; ++j) m = fmaxf(m, s_sc[j * 64 + qi]);
        float ssum = 0.f;
#pragma unroll
        for (int j = 0; j < 27; ++j) ssum += expf(s_sc[j * 64 + qi] - m);
        const float inv = 1.f / ssum;

        // pass 2: per-corner-plane weights, straight-line
        float acc8[8] = {};
        {
            float W[16] = {};
            ADDW(W, 0, zg[0]);
            AXPYPL(W, czo0);
        }
        {
            float W[16] = {};
            ADDW(W, 0, zf[0]);
            ADDW(W, 1, zg[1]);
            AXPYPL(W, czo1);
        }
        {
            float W[16] = {};
            ADDW(W, 1, zf[1]);
            ADDW(W, 2, zg[2]);
            AXPYPL(W, czo2);
        }
        {
            float W[16] = {};
            ADDW(W, 2, zf[2]);
            AXPYPL(W, czo3);
        }

        // epilogue: write o + lepe, |o| partial
        float* dst = ol + ((size_t)(b * Cc + h * HDc + hf * 8)) * Nn + n;
        float sabs = 0.f;
#pragma unroll
        for (int i = 0; i < 8; ++i) {
            float o = acc8[i];
            sabs += fabsf(o);
            size_t off = (size_t)i * Nn;
            dst[off] = o + dst[off];
        }
#pragma unroll
        for (int o = 32; o > 0; o >>= 1) sabs += __shfl_down(sabs, o, 64);
        if ((tid & 63) == 0) s_red[tid >> 6] = sabs;
        __syncthreads();
        if (tid == 0) pe[wid] = s_red[0] + s_red[1] + s_red[2] + s_red[3];
        return;
    }

    // ---------------- dil=2: generic 27x8 path (no structural dedup) ----
    for (int jz = 0; jz < 3; ++jz) {
        int z0 = zi0[jz], z1 = zi1[jz];
        float zfv = zf[jz], zgv = zg[jz];
#pragma unroll
        for (int jy = 0; jy < 3; ++jy) {
#pragma unroll
            for (int jx = 0; jx < 3; ++jx) {
                float d00 = xg[jx] * dot8h(q8, kb + z0 + yi0[jy] + xi0[jx])
                          + xf[jx] * dot8h(q8, kb + z0 + yi0[jy] + xi1[jx]);
                float d01 = xg[jx] * dot8h(q8, kb + z0 + yi1[jy] + xi0[jx])
                          + xf[jx] * dot8h(q8, kb + z0 + yi1[jy] + xi1[jx]);
                float d10 = xg[jx] * dot8h(q8, kb + z1 + yi0[jy] + xi0[jx])
                          + xf[jx] * dot8h(q8, kb + z1 + yi0[jy] + xi1[jx]);
                float d11 = xg[jx] * dot8h(q8, kb + z1 + yi1[jy] + xi0[jx])
                          + xf[jx] * dot8h(q8, kb + z1 + yi1[jy] + xi1[jx]);
                float s = zgv * (yg[jy] * d00 + yf[jy] * d01)
                        + zfv * (yg[jy] * d10 + yf[jy] * d11);
                s += __shfl_xor(s, 1);
                s += __shfl_xor(s, 2);
                if (hf == 0) {
                    int j = jz * 9 + jy * 3 + jx;
                    s_sc[j * 64 + qi] = s * SCALEc + brow[j];
                }
            }
        }
    }
    __syncthreads();

    float m = -1e30f;
#pragma unroll
    for (int j = 0; j < 27; ++j) m = fmaxf(m, s_sc[j * 64 + qi]);
    float ssum = 0.f;
#pragma unroll
    for (int j = 0; j < 27; ++j) ssum += expf(s_sc[j * 64 + qi] - m);
    const float inv = 1.f / ssum;

    float acc8[8] = {};
    for (int jz = 0; jz < 3; ++jz) {
        int z0 = zi0[jz], z1 = zi1[jz];
        float zfv = zf[jz], zgv = zg[jz];
#pragma unroll
        for (int jy = 0; jy < 3; ++jy) {
#pragma unroll
            for (int jx = 0; jx < 3; ++jx) {
                int j = jz * 9 + jy * 3 + jx;
                float aj = expf(s_sc[j * 64 + qi] - m) * inv;
                float wz0 = aj * zgv, wz1 = aj * zfv;
                float w00 = wz0 * yg[jy], w01 = wz0 * yf[jy];
                float w10 = wz1 * yg[jy], w11 = wz1 * yf[jy];
                axpy8h(acc8, w00 * xg[jx], vb + z0 + yi0[jy] + xi0[jx]);
                axpy8h(acc8, w00 * xf[jx], vb + z0 + yi0[jy] + xi1[jx]);
                axpy8h(acc8, w01 * xg[jx], vb + z0 + yi1[jy] + xi0[jx]);
                axpy8h(acc8, w01 * xf[jx], vb + z0 + yi1[jy] + xi1[jx]);
                axpy8h(acc8, w10 * xg[jx], vb + z1 + yi0[jy] + xi0[jx]);
                axpy8h(acc8, w10 * xf[jx], vb + z1 + yi0[jy] + xi1[jx]);
                axpy8h(acc8, w11 * xg[jx], vb + z1 + yi1[jy] + xi0[jx]);
                axpy8h(acc8, w11 * xf[jx], vb + z1 + yi1[jy] + xi1[jx]);
            }
        }
    }

    float* dst = ol + ((size_t)(b * Cc + h * HDc + hf * 8)) * Nn + n;
    float sabs = 0.f;
#pragma unroll
    for (int i = 0; i < 8; ++i) {
        float o = acc8[i];
        sabs += fabsf(o);
        size_t off = (size_t)i * Nn;
        dst[off] = o + dst[off];
    }
#pragma unroll
    for (int o = 32; o > 0; o >>= 1) sabs += __shfl_down(sabs, o, 64);
    if ((tid & 63) == 0) s_red[tid >> 6] = sabs;
    __syncthreads();
    if (tid == 0) pe[wid] = s_red[0] + s_red[1] + s_red[2] + s_red[3];
}

// ---------------------------------------------------------------------------
// K5: final projection GEMM  out = pw @ ol + pb    (ol = o + lepe)
// ---------------------------------------------------------------------------
__global__ __launch_bounds__(256) void gemm_out(
    const float* __restrict__ ol,
    const float* __restrict__ pw, const float* __restrict__ pb,
    float* __restrict__ out)
{
    __shared__ float Wt[32][68];
    __shared__ float Xt[32][68];
    const int tid = threadIdx.x;
    const int RO = blockIdx.y * 64;           // 0..128
    const int CO = blockIdx.x * 64;
    const int b  = CO >> 14;
    const int n0 = CO & 16383;
    const size_t xoff = (size_t)b * Cc * Nn + n0;

    float acc[4][4] = {};
    const int ty = tid >> 4, tx = tid & 15;

    for (int k0 = 0; k0 < 192; k0 += 32) {
#pragma unroll
        for (int i = 0; i < 2; ++i) {
            int li = tid + i * 256;
            int row = li >> 3;
            int kq = (li & 7) * 4;
            float4 wv = *(const float4*)(pw + (size_t)(RO + row) * 192 + k0 + kq);
            Wt[kq + 0][row] = wv.x; Wt[kq + 1][row] = wv.y;
            Wt[kq + 2][row] = wv.z; Wt[kq + 3][row] = wv.w;
        }
#pragma unroll
        for (int i = 0; i < 2; ++i) {
            int li = tid + i * 256;
            int kk = li >> 4;
            int c4 = (li & 15) * 4;
            float4 xv = *(const float4*)(ol + xoff + (size_t)(k0 + kk) * Nn + c4);
            *(float4*)&Xt[kk][c4] = xv;
        }
        __syncthreads();
#pragma unroll
        for (int kk = 0; kk < 32; ++kk) {
            float4 av = *(const float4*)&Wt[kk][ty * 4];
            float4 bv = *(const float4*)&Xt[kk][tx * 4];
            acc[0][0] += av.x * bv.x; acc[0][1] += av.x * bv.y; acc[0][2] += av.x * bv.z; acc[0][3] += av.x * bv.w;
            acc[1][0] += av.y * bv.x; acc[1][1] += av.y * bv.y; acc[1][2] += av.y * bv.z; acc[1][3] += av.y * bv.w;
            acc[2][0] += av.z * bv.x; acc[2][1] += av.z * bv.y; acc[2][2] += av.z * bv.z; acc[2][3] += av.z * bv.w;
            acc[3][0] += av.w * bv.x; acc[3][1] += av.w * bv.y; acc[3][2] += av.w * bv.z; acc[3][3] += av.w * bv.w;
        }
        __syncthreads();
    }
#pragma unroll
    for (int i = 0; i < 4; ++i) {
        int r = RO + ty * 4 + i;
        float bias = pb[r];
#pragma unroll
        for (int j = 0; j < 4; ++j) {
            out[((size_t)(b * Cc + r)) * Nn + n0 + tx * 4 + j] = acc[i][j] + bias;
        }
    }
}

// ---------------------------------------------------------------------------
// Reductions
// ---------------------------------------------------------------------------
__global__ __launch_bounds__(256) void mag_stage1(const float* __restrict__ offs, float* __restrict__ pm) {
    __shared__ float sm[4];
    int g = blockIdx.x >> 3, chunk = blockIdx.x & 7;   // g = bh (0..11)
    int tid = threadIdx.x;
    float s = 0.f;
    for (int i = tid; i < 2048; i += 256) {
        size_t base = ((size_t)g * Nn + chunk * 2048 + i) * 3;
        float a = offs[base], b = offs[base + 1], c = offs[base + 2];
        s += sqrtf(a * a + b * b + c * c);
    }
#pragma unroll
    for (int o = 32; o > 0; o >>= 1) s += __shfl_down(s, o, 64);
    if ((tid & 63) == 0) sm[tid >> 6] = s;
    __syncthreads();
    if (tid == 0) pm[blockIdx.x] = sm[0] + sm[1] + sm[2] + sm[3];
}

__global__ __launch_bounds__(64) void finalize_k(const float* __restrict__ pm, const float* __restrict__ pe,
                                                 float* __restrict__ out) {
    int tid = threadIdx.x;
    if (tid < 12) {
        float s = 0.f;
#pragma unroll
        for (int i = 0; i < 8; ++i) s += pm[tid * 8 + i];
        float mag = s / 16384.f;
        out[OUT_MAG + tid] = mag;
        int b = tid / 6, h = tid % 6;
        out[OUT_GUIDE + b * 8 + h] = mag;
    }
    if (tid < 4) {
        int b = tid >> 1, br = tid & 1;
        float s = 0.f;
        for (int hh = 0; hh < 3; ++hh)
            for (int c = 0; c < 256; ++c)
                s += pe[((b * NHc) + br * 3 + hh) * 256 + c];
        float e = s / 1572864.f;     // 3 heads * 32 dims * 16384 positions
        out[OUT_EN + tid] = e;
        out[OUT_GUIDE + b * 8 + 6 + br] = e;
    }
}

// ---------------------------------------------------------------------------
extern "C" void kernel_launch(void* const* d_in, const int* in_sizes, int n_in,
                              void* d_out, int out_size, void* d_ws, size_t ws_size,
                              hipStream_t stream) {
    const float* x    = (const float*)d_in[0];
    const float* qw   = (const float*)d_in[1];
    const float* qb   = (const float*)d_in[2];
    const float* kw   = (const float*)d_in[3];
    const float* kb   = (const float*)d_in[4];
    const float* vw   = (const float*)d_in[5];
    const float* vb   = (const float*)d_in[6];
    const float* pw   = (const float*)d_in[7];
    const float* pb   = (const float*)d_in[8];
    const float* odw  = (const float*)d_in[9];
    const float* odb  = (const float*)d_in[10];
    const float* lnw  = (const float*)d_in[11];
    const float* lnb  = (const float*)d_in[12];
    const float* opw  = (const float*)d_in[13];
    const float* opb  = (const float*)d_in[14];
    const float* rpew = (const float*)d_in[15];
    const float* rpeb = (const float*)d_in[16];
    const float* bias0 = (const float*)d_in[17];
    const float* bias1 = (const float*)d_in[18];

    float* ws = (float*)d_ws;
    float* q_p  = ws;                            // BIG
    float* q_t  = ws + (size_t)BIG;              // BIG
    __half* kh  = (__half*)(ws + (size_t)2 * BIG);            // BIG halfs
    __half* vh  = (__half*)(ws + (size_t)2 * BIG + BIG / 2);  // BIG halfs
    float* ol   = ws + (size_t)3 * BIG;          // BIG (lepe, then o+lepe)
    float* t_dw = ws + (size_t)4 * BIG;          // BIG
    float* t3   = ws + (size_t)5 * BIG;          // 589824
    float* pm   = t3 + 589824;                   // 96
    float* pe   = pm + 96;                       // 3072

    float* out = (float*)d_out;
    float* offs_out = out + OUT_OFFS;

    gemm_qkv<<<dim3(512, 9), 256, 0, stream>>>(x, qw, qb, kw, kb, vw, vb, q_p, q_t, kh, vh);
    dwconv2<<<24576, 256, 0, stream>>>(q_p, rpew, rpeb, odw, odb, ol, t_dw);
    ln_offs<<<512, 256, 0, stream>>>(t_dw, lnw, lnb, opw, opb, t3, offs_out);
    attn_kernel<<<3072, 256, 0, stream>>>(q_t, kh, vh, t3, bias0, bias1, ol, pe);
    gemm_out<<<dim3(512, 3), 256, 0, stream>>>(ol, pw, pb, out);
    mag_stage1<<<96, 256, 0, stream>>>(offs_out, pm);
    finalize_k<<<1, 64, 0, stream>>>(pm, pe, out);
}